// Round 1
// baseline (1685.649 us; speedup 1.0000x reference)
//
#include <hip/hip_runtime.h>
#include <hip/hip_bf16.h>

// GCN: 2× GCNConv (sym-norm, self-loops) + ReLU, segment_max pool, linear.
// N=100000, E=3200000, G=64, IN=256, H1=64, H2=32. All fp32.

#define NTHREADS 256

// ---------------- deg / dinv ----------------
__global__ __launch_bounds__(NTHREADS) void deg_init_kernel(float* __restrict__ deg, int n) {
    int i = blockIdx.x * NTHREADS + threadIdx.x;
    if (i < n) deg[i] = 1.0f;  // self-loop weight
}

__global__ __launch_bounds__(NTHREADS) void deg_accum_kernel(const int* __restrict__ dst,
                                                             const float* __restrict__ ew,
                                                             float* __restrict__ deg, int nE) {
    int e = blockIdx.x * NTHREADS + threadIdx.x;
    if (e < nE) atomicAdd(&deg[dst[e]], ew[e]);
}

__global__ __launch_bounds__(NTHREADS) void dinv_kernel(float* __restrict__ deg, int n) {
    int i = blockIdx.x * NTHREADS + threadIdx.x;
    if (i < n) deg[i] = rsqrtf(deg[i]);  // deg >= 1 always (self loop)
}

// ---------------- GEMM1: h1[n][64] = x[n][256] @ W1[256][64] ----------------
// Block: 256 threads, tile 64 rows x 64 cols, K-chunks of 32.
__global__ __launch_bounds__(NTHREADS) void gemm1_kernel(const float* __restrict__ x,
                                                         const float* __restrict__ W,
                                                         float* __restrict__ h, int n) {
    __shared__ float xT[32][68];   // [k][row], padded for banks + 16B alignment
    __shared__ float ws[32][64];   // [k][col]
    const int t = threadIdx.x;
    const int row0 = blockIdx.x * 64;
    const int tc4 = (t & 15) * 4;
    const int tr4 = (t >> 4) * 4;
    float acc[4][4] = {};

    const int tx = t & 31;   // k within chunk
    const int ty = t >> 5;   // row group (8 rows stride 8)

    for (int kb = 0; kb < 256; kb += 32) {
        #pragma unroll
        for (int rp = 0; rp < 8; ++rp) {
            int r = ty + rp * 8;
            int grow = row0 + r;
            float v = (grow < n) ? x[(size_t)grow * 256 + kb + tx] : 0.0f;
            xT[tx][r] = v;
        }
        #pragma unroll
        for (int p = 0; p < 8; ++p) {
            int idx = p * 256 + t;
            ws[idx >> 6][idx & 63] = W[(size_t)(kb + (idx >> 6)) * 64 + (idx & 63)];
        }
        __syncthreads();
        #pragma unroll
        for (int kk = 0; kk < 32; ++kk) {
            float4 xv = *(const float4*)&xT[kk][tr4];
            float4 wv = *(const float4*)&ws[kk][tc4];
            acc[0][0] += xv.x * wv.x; acc[0][1] += xv.x * wv.y; acc[0][2] += xv.x * wv.z; acc[0][3] += xv.x * wv.w;
            acc[1][0] += xv.y * wv.x; acc[1][1] += xv.y * wv.y; acc[1][2] += xv.y * wv.z; acc[1][3] += xv.y * wv.w;
            acc[2][0] += xv.z * wv.x; acc[2][1] += xv.z * wv.y; acc[2][2] += xv.z * wv.z; acc[2][3] += xv.z * wv.w;
            acc[3][0] += xv.w * wv.x; acc[3][1] += xv.w * wv.y; acc[3][2] += xv.w * wv.z; acc[3][3] += xv.w * wv.w;
        }
        __syncthreads();
    }
    #pragma unroll
    for (int r = 0; r < 4; ++r) {
        int grow = row0 + tr4 + r;
        if (grow < n) {
            float4 o = make_float4(acc[r][0], acc[r][1], acc[r][2], acc[r][3]);
            *(float4*)&h[(size_t)grow * 64 + tc4] = o;
        }
    }
}

// ---------------- Aggregation 1: agg1[d][j] += norm_e * h1[s][j], 64 feats ----------------
__global__ __launch_bounds__(NTHREADS) void agg1_kernel(const int* __restrict__ src,
                                                        const int* __restrict__ dst,
                                                        const float* __restrict__ ew,
                                                        const float* __restrict__ dinv,
                                                        const float* __restrict__ h1,
                                                        float* __restrict__ agg1, int nE) {
    int idx = blockIdx.x * NTHREADS + threadIdx.x;
    int e = idx >> 6;
    int j = idx & 63;
    if (e >= nE) return;
    int s = src[e], d = dst[e];
    float nw = dinv[s] * ew[e] * dinv[d];
    float v = h1[(size_t)s * 64 + j];
    atomicAdd(&agg1[(size_t)d * 64 + j], nw * v);
}

// ---------------- self-loop + bias + relu (in place on agg1) ----------------
__global__ __launch_bounds__(NTHREADS) void relu1_kernel(float* __restrict__ agg1,
                                                         const float* __restrict__ h1,
                                                         const float* __restrict__ dinv,
                                                         const float* __restrict__ b1, int n) {
    int i = blockIdx.x * NTHREADS + threadIdx.x;
    if (i >= n * 64) return;
    int node = i >> 6, j = i & 63;
    float di = dinv[node];
    float v = agg1[i] + di * di * h1[i] + b1[j];
    agg1[i] = fmaxf(v, 0.0f);
}

// ---------------- GEMM2: h2[n][32] = y1[n][64] @ W2[64][32] ----------------
__global__ __launch_bounds__(NTHREADS) void gemm2_kernel(const float* __restrict__ y1,
                                                         const float* __restrict__ W,
                                                         float* __restrict__ h, int n) {
    __shared__ float xT[64][68];
    __shared__ float ws[64][32];
    const int t = threadIdx.x;
    const int row0 = blockIdx.x * 64;
    const int tc2 = (t & 15) * 2;
    const int tr4 = (t >> 4) * 4;
    float acc[4][2] = {};

    const int tx = t & 63;  // k
    const int ty = t >> 6;  // 0..3
    #pragma unroll
    for (int rp = 0; rp < 16; ++rp) {
        int r = ty * 16 + rp;
        int grow = row0 + r;
        float v = (grow < n) ? y1[(size_t)grow * 64 + tx] : 0.0f;
        xT[tx][r] = v;
    }
    #pragma unroll
    for (int p = 0; p < 8; ++p) {
        int idx = p * 256 + t;
        ws[idx >> 5][idx & 31] = W[idx];
    }
    __syncthreads();
    #pragma unroll
    for (int kk = 0; kk < 64; ++kk) {
        float4 xv = *(const float4*)&xT[kk][tr4];
        float2 wv = *(const float2*)&ws[kk][tc2];
        acc[0][0] += xv.x * wv.x; acc[0][1] += xv.x * wv.y;
        acc[1][0] += xv.y * wv.x; acc[1][1] += xv.y * wv.y;
        acc[2][0] += xv.z * wv.x; acc[2][1] += xv.z * wv.y;
        acc[3][0] += xv.w * wv.x; acc[3][1] += xv.w * wv.y;
    }
    #pragma unroll
    for (int r = 0; r < 4; ++r) {
        int grow = row0 + tr4 + r;
        if (grow < n) {
            float2 o = make_float2(acc[r][0], acc[r][1]);
            *(float2*)&h[(size_t)grow * 32 + tc2] = o;
        }
    }
}

// ---------------- Aggregation 2: agg2[d][j] += norm_e * h2[s][j], 32 feats ----------------
__global__ __launch_bounds__(NTHREADS) void agg2_kernel(const int* __restrict__ src,
                                                        const int* __restrict__ dst,
                                                        const float* __restrict__ ew,
                                                        const float* __restrict__ dinv,
                                                        const float* __restrict__ h2,
                                                        float* __restrict__ agg2, int nE) {
    int idx = blockIdx.x * NTHREADS + threadIdx.x;
    int e = idx >> 5;
    int j = idx & 31;
    if (e >= nE) return;
    int s = src[e], d = dst[e];
    float nw = dinv[s] * ew[e] * dinv[d];
    float v = h2[(size_t)s * 32 + j];
    atomicAdd(&agg2[(size_t)d * 32 + j], nw * v);
}

// ---------------- self-loop + bias + relu + segment_max pool ----------------
__global__ __launch_bounds__(NTHREADS) void relu2_pool_kernel(const float* __restrict__ agg2,
                                                              const float* __restrict__ h2,
                                                              const float* __restrict__ dinv,
                                                              const float* __restrict__ b2,
                                                              const int* __restrict__ batch,
                                                              unsigned int* __restrict__ pooled,
                                                              int n) {
    int i = blockIdx.x * NTHREADS + threadIdx.x;
    if (i >= n * 32) return;
    int node = i >> 5, j = i & 31;
    float di = dinv[node];
    float v = fmaxf(agg2[i] + di * di * h2[i] + b2[j], 0.0f);
    // v >= 0 always, so uint bit-pattern compare == float compare; init 0 is fine.
    atomicMax(&pooled[(size_t)batch[node] * 32 + j], __float_as_uint(v));
}

// ---------------- final: out[64][4] = pooled[64][32] @ Wlin[32][4] + blin ----------------
__global__ __launch_bounds__(NTHREADS) void final_kernel(const float* __restrict__ pooled,
                                                         const float* __restrict__ Wlin,
                                                         const float* __restrict__ blin,
                                                         float* __restrict__ out) {
    int t = threadIdx.x;  // 256 = 64 graphs * 4 cols
    int g = t >> 2, c = t & 3;
    float s = blin[c];
    #pragma unroll
    for (int j = 0; j < 32; ++j) s += pooled[g * 32 + j] * Wlin[j * 4 + c];
    out[g * 4 + c] = s;
}

extern "C" void kernel_launch(void* const* d_in, const int* in_sizes, int n_in,
                              void* d_out, int out_size, void* d_ws, size_t ws_size,
                              hipStream_t stream) {
    const float* x    = (const float*)d_in[0];
    const int*   ei   = (const int*)d_in[1];
    const float* ew   = (const float*)d_in[2];
    const int*   batch= (const int*)d_in[3];
    const float* W1   = (const float*)d_in[4];
    const float* b1   = (const float*)d_in[5];
    const float* W2   = (const float*)d_in[6];
    const float* b2   = (const float*)d_in[7];
    const float* Wlin = (const float*)d_in[8];
    const float* blin = (const float*)d_in[9];
    float* out = (float*)d_out;

    const int E = in_sizes[2];       // 3200000
    const int n = in_sizes[3];       // 100000
    const int* src = ei;
    const int* dst = ei + E;

    // workspace layout (floats)
    float* ws = (float*)d_ws;
    size_t off = 0;
    float* deg  = ws + off; off += ((size_t)(n + 255) / 256) * 256;   // dinv in-place
    float* h1   = ws + off; off += (size_t)n * 64;
    float* agg1 = ws + off; off += (size_t)n * 64;
    float* h2   = ws + off; off += (size_t)n * 32;
    float* agg2 = ws + off; off += (size_t)n * 32;
    float* pooled = ws + off; off += 64 * 32;

    hipMemsetAsync(agg1, 0, (size_t)n * 64 * sizeof(float), stream);
    hipMemsetAsync(agg2, 0, (size_t)n * 32 * sizeof(float), stream);
    hipMemsetAsync(pooled, 0, 64 * 32 * sizeof(float), stream);

    deg_init_kernel<<<(n + 255) / 256, NTHREADS, 0, stream>>>(deg, n);
    deg_accum_kernel<<<(E + 255) / 256, NTHREADS, 0, stream>>>(dst, ew, deg, E);
    dinv_kernel<<<(n + 255) / 256, NTHREADS, 0, stream>>>(deg, n);

    gemm1_kernel<<<(n + 63) / 64, NTHREADS, 0, stream>>>(x, W1, h1, n);

    agg1_kernel<<<(unsigned)(((size_t)E * 64 + 255) / 256), NTHREADS, 0, stream>>>(
        src, dst, ew, deg, h1, agg1, E);
    relu1_kernel<<<(n * 64 + 255) / 256, NTHREADS, 0, stream>>>(agg1, h1, deg, b1, n);

    gemm2_kernel<<<(n + 63) / 64, NTHREADS, 0, stream>>>(agg1, W2, h2, n);

    agg2_kernel<<<(unsigned)(((size_t)E * 32 + 255) / 256), NTHREADS, 0, stream>>>(
        src, dst, ew, deg, h2, agg2, E);
    relu2_pool_kernel<<<(n * 32 + 255) / 256, NTHREADS, 0, stream>>>(
        agg2, h2, deg, b2, batch, (unsigned int*)pooled, n);

    final_kernel<<<1, NTHREADS, 0, stream>>>(pooled, Wlin, blin, out);
}

// Round 2
// 1210.989 us; speedup vs baseline: 1.3920x; 1.3920x over previous
//
#include <hip/hip_runtime.h>
#include <hip/hip_bf16.h>

// GCN: 2x GCNConv (sym-norm, self-loops) + ReLU, segment_max pool, linear.
// N=100000, E=3200000, G=64, IN=256, H1=64, H2=32. All fp32.
// Strategy: build CSR-by-dst once per launch, gather-accumulate (no fp atomics).

#define NTHREADS 256
#define SCAN_CHUNK 1024

// ---------------- deg init (self-loop weight 1) ----------------
__global__ __launch_bounds__(NTHREADS) void deg_init_kernel(float* __restrict__ deg, int n) {
    int i = blockIdx.x * NTHREADS + threadIdx.x;
    if (i < n) deg[i] = 1.0f;
}

// ---------------- histogram of dst + weighted degree ----------------
__global__ __launch_bounds__(NTHREADS) void hist_kernel(const int* __restrict__ dst,
                                                        const float* __restrict__ ew,
                                                        int* __restrict__ cnt,
                                                        float* __restrict__ deg, int nE) {
    int e = blockIdx.x * NTHREADS + threadIdx.x;
    if (e < nE) {
        int d = dst[e];
        atomicAdd(&cnt[d], 1);
        atomicAdd(&deg[d], ew[e]);
    }
}

__global__ __launch_bounds__(NTHREADS) void dinv_kernel(float* __restrict__ deg, int n) {
    int i = blockIdx.x * NTHREADS + threadIdx.x;
    if (i < n) deg[i] = rsqrtf(deg[i]);  // deg >= 1 (self loop)
}

// ---------------- exclusive scan of cnt -> rowptr (3 kernels) ----------------
__global__ __launch_bounds__(NTHREADS) void scan1_kernel(const int* __restrict__ cnt,
                                                         int* __restrict__ rowptr,
                                                         int* __restrict__ bsum, int n) {
    __shared__ int tmp[NTHREADS];
    const int base = blockIdx.x * SCAN_CHUNK;
    const int t = threadIdx.x;
    int v[4];
    #pragma unroll
    for (int k = 0; k < 4; ++k) {
        int i = base + t * 4 + k;
        v[k] = (i < n) ? cnt[i] : 0;
    }
    int s = v[0] + v[1] + v[2] + v[3];
    tmp[t] = s;
    __syncthreads();
    for (int off = 1; off < NTHREADS; off <<= 1) {
        int val = (t >= off) ? tmp[t - off] : 0;
        __syncthreads();
        tmp[t] += val;
        __syncthreads();
    }
    int excl = tmp[t] - s;
    if (t == NTHREADS - 1) bsum[blockIdx.x] = tmp[NTHREADS - 1];
    int run = excl;
    #pragma unroll
    for (int k = 0; k < 4; ++k) {
        int i = base + t * 4 + k;
        if (i < n) rowptr[i] = run;
        run += v[k];
    }
}

__global__ __launch_bounds__(NTHREADS) void scan2_kernel(int* __restrict__ bsum, int nb) {
    __shared__ int tmp[NTHREADS];
    int t = threadIdx.x;
    int v = (t < nb) ? bsum[t] : 0;
    tmp[t] = v;
    __syncthreads();
    for (int off = 1; off < NTHREADS; off <<= 1) {
        int val = (t >= off) ? tmp[t - off] : 0;
        __syncthreads();
        tmp[t] += val;
        __syncthreads();
    }
    if (t < nb) bsum[t] = tmp[t] - v;  // exclusive
}

__global__ __launch_bounds__(NTHREADS) void scan3_kernel(int* __restrict__ rowptr,
                                                         const int* __restrict__ bsum,
                                                         int n, int E) {
    int i = blockIdx.x * NTHREADS + threadIdx.x;
    if (i < n) rowptr[i] += bsum[i / SCAN_CHUNK];
    if (i == 0) rowptr[n] = E;
}

// ---------------- scatter edges into CSR slots, pre-scaled weight ----------------
__global__ __launch_bounds__(NTHREADS) void scatter_kernel(const int* __restrict__ src,
                                                           const int* __restrict__ dst,
                                                           const float* __restrict__ ew,
                                                           const float* __restrict__ dinv,
                                                           const int* __restrict__ rowptr,
                                                           int* __restrict__ fill,
                                                           int2* __restrict__ meta, int nE) {
    int e = blockIdx.x * NTHREADS + threadIdx.x;
    if (e >= nE) return;
    int s = src[e], d = dst[e];
    int pos = rowptr[d] + atomicAdd(&fill[d], 1);
    float w = dinv[s] * ew[e] * dinv[d];
    meta[pos] = make_int2(s, __float_as_int(w));
}

// ---------------- GEMM1: h1[n][64] = x[n][256] @ W1[256][64] ----------------
__global__ __launch_bounds__(NTHREADS) void gemm1_kernel(const float* __restrict__ x,
                                                         const float* __restrict__ W,
                                                         float* __restrict__ h, int n) {
    __shared__ float xT[32][68];
    __shared__ float ws[32][64];
    const int t = threadIdx.x;
    const int row0 = blockIdx.x * 64;
    const int tc4 = (t & 15) * 4;
    const int tr4 = (t >> 4) * 4;
    float acc[4][4] = {};

    const int tx = t & 31;
    const int ty = t >> 5;

    for (int kb = 0; kb < 256; kb += 32) {
        #pragma unroll
        for (int rp = 0; rp < 8; ++rp) {
            int r = ty + rp * 8;
            int grow = row0 + r;
            float v = (grow < n) ? x[(size_t)grow * 256 + kb + tx] : 0.0f;
            xT[tx][r] = v;
        }
        #pragma unroll
        for (int p = 0; p < 8; ++p) {
            int idx = p * 256 + t;
            ws[idx >> 6][idx & 63] = W[(size_t)(kb + (idx >> 6)) * 64 + (idx & 63)];
        }
        __syncthreads();
        #pragma unroll
        for (int kk = 0; kk < 32; ++kk) {
            float4 xv = *(const float4*)&xT[kk][tr4];
            float4 wv = *(const float4*)&ws[kk][tc4];
            acc[0][0] += xv.x * wv.x; acc[0][1] += xv.x * wv.y; acc[0][2] += xv.x * wv.z; acc[0][3] += xv.x * wv.w;
            acc[1][0] += xv.y * wv.x; acc[1][1] += xv.y * wv.y; acc[1][2] += xv.y * wv.z; acc[1][3] += xv.y * wv.w;
            acc[2][0] += xv.z * wv.x; acc[2][1] += xv.z * wv.y; acc[2][2] += xv.z * wv.z; acc[2][3] += xv.z * wv.w;
            acc[3][0] += xv.w * wv.x; acc[3][1] += xv.w * wv.y; acc[3][2] += xv.w * wv.z; acc[3][3] += xv.w * wv.w;
        }
        __syncthreads();
    }
    #pragma unroll
    for (int r = 0; r < 4; ++r) {
        int grow = row0 + tr4 + r;
        if (grow < n) {
            float4 o = make_float4(acc[r][0], acc[r][1], acc[r][2], acc[r][3]);
            *(float4*)&h[(size_t)grow * 64 + tc4] = o;
        }
    }
}

// ---------------- agg1 (CSR gather) + self-loop + bias + relu -> y1 ----------------
__global__ __launch_bounds__(NTHREADS) void agg1_csr_kernel(const int* __restrict__ rowptr,
                                                            const int2* __restrict__ meta,
                                                            const float* __restrict__ h1,
                                                            const float* __restrict__ dinv,
                                                            const float* __restrict__ b1,
                                                            float* __restrict__ y1, int n) {
    int idx = blockIdx.x * NTHREADS + threadIdx.x;
    int node = idx >> 6, j = idx & 63;
    if (node >= n) return;
    int beg = rowptr[node], end = rowptr[node + 1];
    float di = dinv[node];
    float acc = di * di * h1[(size_t)node * 64 + j];
    int k = beg;
    for (; k + 1 < end; k += 2) {
        int2 m0 = meta[k];
        int2 m1 = meta[k + 1];
        acc += __int_as_float(m0.y) * h1[(size_t)m0.x * 64 + j];
        acc += __int_as_float(m1.y) * h1[(size_t)m1.x * 64 + j];
    }
    if (k < end) {
        int2 m = meta[k];
        acc += __int_as_float(m.y) * h1[(size_t)m.x * 64 + j];
    }
    y1[idx] = fmaxf(acc + b1[j], 0.0f);
}

// ---------------- GEMM2: h2[n][32] = y1[n][64] @ W2[64][32] ----------------
__global__ __launch_bounds__(NTHREADS) void gemm2_kernel(const float* __restrict__ y1,
                                                         const float* __restrict__ W,
                                                         float* __restrict__ h, int n) {
    __shared__ float xT[64][68];
    __shared__ float ws[64][32];
    const int t = threadIdx.x;
    const int row0 = blockIdx.x * 64;
    const int tc2 = (t & 15) * 2;
    const int tr4 = (t >> 4) * 4;
    float acc[4][2] = {};

    const int tx = t & 63;
    const int ty = t >> 6;
    #pragma unroll
    for (int rp = 0; rp < 16; ++rp) {
        int r = ty * 16 + rp;
        int grow = row0 + r;
        float v = (grow < n) ? y1[(size_t)grow * 64 + tx] : 0.0f;
        xT[tx][r] = v;
    }
    #pragma unroll
    for (int p = 0; p < 8; ++p) {
        int idx = p * 256 + t;
        ws[idx >> 5][idx & 31] = W[idx];
    }
    __syncthreads();
    #pragma unroll
    for (int kk = 0; kk < 64; ++kk) {
        float4 xv = *(const float4*)&xT[kk][tr4];
        float2 wv = *(const float2*)&ws[kk][tc2];
        acc[0][0] += xv.x * wv.x; acc[0][1] += xv.x * wv.y;
        acc[1][0] += xv.y * wv.x; acc[1][1] += xv.y * wv.y;
        acc[2][0] += xv.z * wv.x; acc[2][1] += xv.z * wv.y;
        acc[3][0] += xv.w * wv.x; acc[3][1] += xv.w * wv.y;
    }
    #pragma unroll
    for (int r = 0; r < 4; ++r) {
        int grow = row0 + tr4 + r;
        if (grow < n) {
            float2 o = make_float2(acc[r][0], acc[r][1]);
            *(float2*)&h[(size_t)grow * 32 + tc2] = o;
        }
    }
}

// ---- agg2 (CSR gather) + self-loop + bias + relu + segment_max pool ----
__global__ __launch_bounds__(NTHREADS) void agg2_csr_pool_kernel(const int* __restrict__ rowptr,
                                                                 const int2* __restrict__ meta,
                                                                 const float* __restrict__ h2,
                                                                 const float* __restrict__ dinv,
                                                                 const float* __restrict__ b2,
                                                                 const int* __restrict__ batch,
                                                                 unsigned int* __restrict__ pooled,
                                                                 int n) {
    int idx = blockIdx.x * NTHREADS + threadIdx.x;
    int node = idx >> 5, j = idx & 31;
    if (node >= n) return;
    int beg = rowptr[node], end = rowptr[node + 1];
    float di = dinv[node];
    float acc = di * di * h2[(size_t)node * 32 + j];
    int k = beg;
    for (; k + 1 < end; k += 2) {
        int2 m0 = meta[k];
        int2 m1 = meta[k + 1];
        acc += __int_as_float(m0.y) * h2[(size_t)m0.x * 32 + j];
        acc += __int_as_float(m1.y) * h2[(size_t)m1.x * 32 + j];
    }
    if (k < end) {
        int2 m = meta[k];
        acc += __int_as_float(m.y) * h2[(size_t)m.x * 32 + j];
    }
    float v = fmaxf(acc + b2[j], 0.0f);
    // v >= 0, so uint bit compare == float compare; pooled zero-initialized.
    atomicMax(&pooled[(size_t)batch[node] * 32 + j], __float_as_uint(v));
}

// ---------------- final: out[64][4] = pooled[64][32] @ Wlin[32][4] + blin ----------------
__global__ __launch_bounds__(NTHREADS) void final_kernel(const float* __restrict__ pooled,
                                                         const float* __restrict__ Wlin,
                                                         const float* __restrict__ blin,
                                                         float* __restrict__ out) {
    int t = threadIdx.x;  // 256 = 64 graphs * 4 cols
    int g = t >> 2, c = t & 3;
    float s = blin[c];
    #pragma unroll
    for (int j = 0; j < 32; ++j) s += pooled[g * 32 + j] * Wlin[j * 4 + c];
    out[g * 4 + c] = s;
}

extern "C" void kernel_launch(void* const* d_in, const int* in_sizes, int n_in,
                              void* d_out, int out_size, void* d_ws, size_t ws_size,
                              hipStream_t stream) {
    const float* x     = (const float*)d_in[0];
    const int*   ei    = (const int*)d_in[1];
    const float* ew    = (const float*)d_in[2];
    const int*   batch = (const int*)d_in[3];
    const float* W1    = (const float*)d_in[4];
    const float* b1    = (const float*)d_in[5];
    const float* W2    = (const float*)d_in[6];
    const float* b2    = (const float*)d_in[7];
    const float* Wlin  = (const float*)d_in[8];
    const float* blin  = (const float*)d_in[9];
    float* out = (float*)d_out;

    const int E = in_sizes[2];   // 3200000
    const int n = in_sizes[3];   // 100000
    const int* src = ei;
    const int* dst = ei + E;

    const int nchunks = (n + SCAN_CHUNK - 1) / SCAN_CHUNK;  // 98

    // workspace layout (4-byte units), 256B-aligned chunks
    auto al = [](size_t v) { return (v + 63) & ~(size_t)63; };
    float* ws = (float*)d_ws;
    size_t off = 0;
    float* deg    = ws + off; off += al(n);          // becomes dinv in place
    int*   cnt    = (int*)(ws + off); off += al(n);
    int*   fill   = (int*)(ws + off); off += al(n);
    int*   rowptr = (int*)(ws + off); off += al(n + 1);
    int*   bsum   = (int*)(ws + off); off += al(256);
    int2*  meta   = (int2*)(ws + off); off += al((size_t)E * 2);
    float* h1     = ws + off; off += al((size_t)n * 64);   // reused as h2 after agg1
    float* y1     = ws + off; off += al((size_t)n * 64);
    float* pooled = ws + off; off += al(64 * 32);
    float* h2 = h1;  // h1 dead after agg1_csr; gemm2 overwrites with h2

    hipMemsetAsync(cnt, 0, (size_t)n * sizeof(int), stream);
    hipMemsetAsync(fill, 0, (size_t)n * sizeof(int), stream);
    hipMemsetAsync(pooled, 0, 64 * 32 * sizeof(float), stream);

    // degree + histogram + dinv
    deg_init_kernel<<<(n + 255) / 256, NTHREADS, 0, stream>>>(deg, n);
    hist_kernel<<<(E + 255) / 256, NTHREADS, 0, stream>>>(dst, ew, cnt, deg, E);
    dinv_kernel<<<(n + 255) / 256, NTHREADS, 0, stream>>>(deg, n);

    // rowptr = exclusive_scan(cnt)
    scan1_kernel<<<nchunks, NTHREADS, 0, stream>>>(cnt, rowptr, bsum, n);
    scan2_kernel<<<1, NTHREADS, 0, stream>>>(bsum, nchunks);
    scan3_kernel<<<(n + 255) / 256, NTHREADS, 0, stream>>>(rowptr, bsum, n, E);

    // scatter edges into CSR (pre-scaled norm weights)
    scatter_kernel<<<(E + 255) / 256, NTHREADS, 0, stream>>>(src, dst, ew, deg, rowptr, fill, meta, E);

    // layer 1
    gemm1_kernel<<<(n + 63) / 64, NTHREADS, 0, stream>>>(x, W1, h1, n);
    agg1_csr_kernel<<<(int)(((size_t)n * 64 + 255) / 256), NTHREADS, 0, stream>>>(
        rowptr, meta, h1, deg, b1, y1, n);

    // layer 2
    gemm2_kernel<<<(n + 63) / 64, NTHREADS, 0, stream>>>(y1, W2, h2, n);
    agg2_csr_pool_kernel<<<(int)(((size_t)n * 32 + 255) / 256), NTHREADS, 0, stream>>>(
        rowptr, meta, h2, deg, b2, batch, (unsigned int*)pooled, n);

    final_kernel<<<1, NTHREADS, 0, stream>>>(pooled, Wlin, blin, out);
}

// Round 3
// 926.001 us; speedup vs baseline: 1.8204x; 1.3078x over previous
//
#include <hip/hip_runtime.h>
#include <hip/hip_bf16.h>

// GCN: 2x GCNConv (sym-norm, self-loops) + ReLU, segment_max pool, linear.
// N=100000, E=3200000, G=64, IN=256, H1=64, H2=32. All fp32.
// CSR-by-dst build once, then wave-per-node gather with multi-way edge split:
//   agg1: 16 lanes x float4 feats, 4-way edge split, shfl_xor combine
//   agg2:  8 lanes x float4 feats, 8-way edge split, shfl_xor combine + LDS pool

#define NTHREADS 256
#define SCAN_CHUNK 1024

// ---------------- deg init (self-loop weight 1) ----------------
__global__ __launch_bounds__(NTHREADS) void deg_init_kernel(float* __restrict__ deg, int n) {
    int i = blockIdx.x * NTHREADS + threadIdx.x;
    if (i < n) deg[i] = 1.0f;
}

// ---------------- histogram of dst + weighted degree ----------------
__global__ __launch_bounds__(NTHREADS) void hist_kernel(const int* __restrict__ dst,
                                                        const float* __restrict__ ew,
                                                        int* __restrict__ cnt,
                                                        float* __restrict__ deg, int nE) {
    int e = blockIdx.x * NTHREADS + threadIdx.x;
    if (e < nE) {
        int d = dst[e];
        atomicAdd(&cnt[d], 1);
        atomicAdd(&deg[d], ew[e]);
    }
}

__global__ __launch_bounds__(NTHREADS) void dinv_kernel(float* __restrict__ deg, int n) {
    int i = blockIdx.x * NTHREADS + threadIdx.x;
    if (i < n) deg[i] = rsqrtf(deg[i]);  // deg >= 1 (self loop)
}

// ---------------- exclusive scan of cnt -> rowptr ----------------
__global__ __launch_bounds__(NTHREADS) void scan1_kernel(const int* __restrict__ cnt,
                                                         int* __restrict__ rowptr,
                                                         int* __restrict__ bsum, int n) {
    __shared__ int tmp[NTHREADS];
    const int base = blockIdx.x * SCAN_CHUNK;
    const int t = threadIdx.x;
    int v[4];
    #pragma unroll
    for (int k = 0; k < 4; ++k) {
        int i = base + t * 4 + k;
        v[k] = (i < n) ? cnt[i] : 0;
    }
    int s = v[0] + v[1] + v[2] + v[3];
    tmp[t] = s;
    __syncthreads();
    for (int off = 1; off < NTHREADS; off <<= 1) {
        int val = (t >= off) ? tmp[t - off] : 0;
        __syncthreads();
        tmp[t] += val;
        __syncthreads();
    }
    int excl = tmp[t] - s;
    if (t == NTHREADS - 1) bsum[blockIdx.x] = tmp[NTHREADS - 1];
    int run = excl;
    #pragma unroll
    for (int k = 0; k < 4; ++k) {
        int i = base + t * 4 + k;
        if (i < n) rowptr[i] = run;
        run += v[k];
    }
}

__global__ __launch_bounds__(NTHREADS) void scan2_kernel(int* __restrict__ bsum, int nb) {
    __shared__ int tmp[NTHREADS];
    int t = threadIdx.x;
    int v = (t < nb) ? bsum[t] : 0;
    tmp[t] = v;
    __syncthreads();
    for (int off = 1; off < NTHREADS; off <<= 1) {
        int val = (t >= off) ? tmp[t - off] : 0;
        __syncthreads();
        tmp[t] += val;
        __syncthreads();
    }
    if (t < nb) bsum[t] = tmp[t] - v;  // exclusive
}

__global__ __launch_bounds__(NTHREADS) void scan3_kernel(int* __restrict__ rowptr,
                                                         const int* __restrict__ bsum,
                                                         int n, int E) {
    int i = blockIdx.x * NTHREADS + threadIdx.x;
    if (i < n) rowptr[i] += bsum[i / SCAN_CHUNK];
    if (i == 0) rowptr[n] = E;
}

// ---------------- scatter edges into CSR slots, pre-scaled weight ----------------
// rowfill starts as a copy of rowptr; atomicAdd hands out slots directly.
__global__ __launch_bounds__(NTHREADS) void scatter_kernel(const int* __restrict__ src,
                                                           const int* __restrict__ dst,
                                                           const float* __restrict__ ew,
                                                           const float* __restrict__ dinv,
                                                           int* __restrict__ rowfill,
                                                           int2* __restrict__ meta, int nE) {
    int e = blockIdx.x * NTHREADS + threadIdx.x;
    if (e >= nE) return;
    int s = src[e], d = dst[e];
    int pos = atomicAdd(&rowfill[d], 1);
    float w = dinv[s] * ew[e] * dinv[d];
    meta[pos] = make_int2(s, __float_as_int(w));
}

// ---------------- GEMM1: h1[n][64] = x[n][256] @ W1[256][64] ----------------
__global__ __launch_bounds__(NTHREADS) void gemm1_kernel(const float* __restrict__ x,
                                                         const float* __restrict__ W,
                                                         float* __restrict__ h, int n) {
    __shared__ float xT[32][68];
    __shared__ float ws[32][64];
    const int t = threadIdx.x;
    const int row0 = blockIdx.x * 64;
    const int tc4 = (t & 15) * 4;
    const int tr4 = (t >> 4) * 4;
    float acc[4][4] = {};

    const int tx = t & 31;
    const int ty = t >> 5;

    for (int kb = 0; kb < 256; kb += 32) {
        #pragma unroll
        for (int rp = 0; rp < 8; ++rp) {
            int r = ty + rp * 8;
            int grow = row0 + r;
            float v = (grow < n) ? x[(size_t)grow * 256 + kb + tx] : 0.0f;
            xT[tx][r] = v;
        }
        #pragma unroll
        for (int p = 0; p < 8; ++p) {
            int idx = p * 256 + t;
            ws[idx >> 6][idx & 63] = W[(size_t)(kb + (idx >> 6)) * 64 + (idx & 63)];
        }
        __syncthreads();
        #pragma unroll
        for (int kk = 0; kk < 32; ++kk) {
            float4 xv = *(const float4*)&xT[kk][tr4];
            float4 wv = *(const float4*)&ws[kk][tc4];
            acc[0][0] += xv.x * wv.x; acc[0][1] += xv.x * wv.y; acc[0][2] += xv.x * wv.z; acc[0][3] += xv.x * wv.w;
            acc[1][0] += xv.y * wv.x; acc[1][1] += xv.y * wv.y; acc[1][2] += xv.y * wv.z; acc[1][3] += xv.y * wv.w;
            acc[2][0] += xv.z * wv.x; acc[2][1] += xv.z * wv.y; acc[2][2] += xv.z * wv.z; acc[2][3] += xv.z * wv.w;
            acc[3][0] += xv.w * wv.x; acc[3][1] += xv.w * wv.y; acc[3][2] += xv.w * wv.z; acc[3][3] += xv.w * wv.w;
        }
        __syncthreads();
    }
    #pragma unroll
    for (int r = 0; r < 4; ++r) {
        int grow = row0 + tr4 + r;
        if (grow < n) {
            float4 o = make_float4(acc[r][0], acc[r][1], acc[r][2], acc[r][3]);
            *(float4*)&h[(size_t)grow * 64 + tc4] = o;
        }
    }
}

// ---- agg1: wave-per-node, 16 lanes x float4, 4-way edge split ----
__global__ __launch_bounds__(NTHREADS) void agg1_csr_kernel(const int* __restrict__ rowptr,
                                                            const int2* __restrict__ meta,
                                                            const float* __restrict__ h1,
                                                            const float* __restrict__ dinv,
                                                            const float* __restrict__ b1,
                                                            float* __restrict__ y1, int n) {
    const int wid = (blockIdx.x * NTHREADS + threadIdx.x) >> 6;  // node
    if (wid >= n) return;
    const int l = threadIdx.x & 63;
    const int fg = l & 15, eg = l >> 4;
    const int j4 = fg * 4;
    const int beg = rowptr[wid], end = rowptr[wid + 1];
    const float di = dinv[wid];
    const float4 selfv = *(const float4*)&h1[(size_t)wid * 64 + j4];

    float4 acc = make_float4(0.f, 0.f, 0.f, 0.f);
    int k = beg + eg;
    for (; k + 4 < end; k += 8) {
        int2 m0 = meta[k];
        int2 m1 = meta[k + 4];
        float4 v0 = *(const float4*)&h1[(size_t)m0.x * 64 + j4];
        float4 v1 = *(const float4*)&h1[(size_t)m1.x * 64 + j4];
        float w0 = __int_as_float(m0.y), w1 = __int_as_float(m1.y);
        acc.x = fmaf(w0, v0.x, acc.x); acc.y = fmaf(w0, v0.y, acc.y);
        acc.z = fmaf(w0, v0.z, acc.z); acc.w = fmaf(w0, v0.w, acc.w);
        acc.x = fmaf(w1, v1.x, acc.x); acc.y = fmaf(w1, v1.y, acc.y);
        acc.z = fmaf(w1, v1.z, acc.z); acc.w = fmaf(w1, v1.w, acc.w);
    }
    if (k < end) {
        int2 m = meta[k];
        float4 v = *(const float4*)&h1[(size_t)m.x * 64 + j4];
        float w = __int_as_float(m.y);
        acc.x = fmaf(w, v.x, acc.x); acc.y = fmaf(w, v.y, acc.y);
        acc.z = fmaf(w, v.z, acc.z); acc.w = fmaf(w, v.w, acc.w);
    }
    // combine the 4 edge groups (lanes differing in bits 4,5)
    #pragma unroll
    for (int m = 16; m <= 32; m <<= 1) {
        acc.x += __shfl_xor(acc.x, m);
        acc.y += __shfl_xor(acc.y, m);
        acc.z += __shfl_xor(acc.z, m);
        acc.w += __shfl_xor(acc.w, m);
    }
    if (eg == 0) {
        float di2 = di * di;
        float4 bb = *(const float4*)&b1[j4];
        float4 r;
        r.x = fmaxf(fmaf(di2, selfv.x, acc.x) + bb.x, 0.f);
        r.y = fmaxf(fmaf(di2, selfv.y, acc.y) + bb.y, 0.f);
        r.z = fmaxf(fmaf(di2, selfv.z, acc.z) + bb.z, 0.f);
        r.w = fmaxf(fmaf(di2, selfv.w, acc.w) + bb.w, 0.f);
        *(float4*)&y1[(size_t)wid * 64 + j4] = r;
    }
}

// ---------------- GEMM2: h2[n][32] = y1[n][64] @ W2[64][32] ----------------
__global__ __launch_bounds__(NTHREADS) void gemm2_kernel(const float* __restrict__ y1,
                                                         const float* __restrict__ W,
                                                         float* __restrict__ h, int n) {
    __shared__ float xT[64][68];
    __shared__ float ws[64][32];
    const int t = threadIdx.x;
    const int row0 = blockIdx.x * 64;
    const int tc2 = (t & 15) * 2;
    const int tr4 = (t >> 4) * 4;
    float acc[4][2] = {};

    const int tx = t & 63;
    const int ty = t >> 6;
    #pragma unroll
    for (int rp = 0; rp < 16; ++rp) {
        int r = ty * 16 + rp;
        int grow = row0 + r;
        float v = (grow < n) ? y1[(size_t)grow * 64 + tx] : 0.0f;
        xT[tx][r] = v;
    }
    #pragma unroll
    for (int p = 0; p < 8; ++p) {
        int idx = p * 256 + t;
        ws[idx >> 5][idx & 31] = W[idx];
    }
    __syncthreads();
    #pragma unroll
    for (int kk = 0; kk < 64; ++kk) {
        float4 xv = *(const float4*)&xT[kk][tr4];
        float2 wv = *(const float2*)&ws[kk][tc2];
        acc[0][0] += xv.x * wv.x; acc[0][1] += xv.x * wv.y;
        acc[1][0] += xv.y * wv.x; acc[1][1] += xv.y * wv.y;
        acc[2][0] += xv.z * wv.x; acc[2][1] += xv.z * wv.y;
        acc[3][0] += xv.w * wv.x; acc[3][1] += xv.w * wv.y;
    }
    #pragma unroll
    for (int r = 0; r < 4; ++r) {
        int grow = row0 + tr4 + r;
        if (grow < n) {
            float2 o = make_float2(acc[r][0], acc[r][1]);
            *(float2*)&h[(size_t)grow * 32 + tc2] = o;
        }
    }
}

// ---- agg2: wave-per-node, 8 lanes x float4, 8-way edge split, LDS pool ----
__global__ __launch_bounds__(NTHREADS) void agg2_csr_pool_kernel(const int* __restrict__ rowptr,
                                                                 const int2* __restrict__ meta,
                                                                 const float* __restrict__ h2,
                                                                 const float* __restrict__ dinv,
                                                                 const float* __restrict__ b2,
                                                                 const int* __restrict__ batch,
                                                                 unsigned int* __restrict__ pooled,
                                                                 int n) {
    __shared__ float smax[4][32];
    __shared__ int sb[4];
    const int w = threadIdx.x >> 6;            // wave in block
    const int l = threadIdx.x & 63;
    const int node = blockIdx.x * 4 + w;
    const bool active = node < n;
    const int fg = l & 7, eg = l >> 3;
    const int j4 = fg * 4;

    if (l == 0) sb[w] = active ? batch[node] : -1;

    if (active) {
        const int beg = rowptr[node], end = rowptr[node + 1];
        const float di = dinv[node];
        const float4 selfv = *(const float4*)&h2[(size_t)node * 32 + j4];

        float4 acc = make_float4(0.f, 0.f, 0.f, 0.f);
        int k = beg + eg;
        for (; k + 8 < end; k += 16) {
            int2 m0 = meta[k];
            int2 m1 = meta[k + 8];
            float4 v0 = *(const float4*)&h2[(size_t)m0.x * 32 + j4];
            float4 v1 = *(const float4*)&h2[(size_t)m1.x * 32 + j4];
            float w0 = __int_as_float(m0.y), w1 = __int_as_float(m1.y);
            acc.x = fmaf(w0, v0.x, acc.x); acc.y = fmaf(w0, v0.y, acc.y);
            acc.z = fmaf(w0, v0.z, acc.z); acc.w = fmaf(w0, v0.w, acc.w);
            acc.x = fmaf(w1, v1.x, acc.x); acc.y = fmaf(w1, v1.y, acc.y);
            acc.z = fmaf(w1, v1.z, acc.z); acc.w = fmaf(w1, v1.w, acc.w);
        }
        if (k < end) {
            int2 m = meta[k];
            float4 v = *(const float4*)&h2[(size_t)m.x * 32 + j4];
            float wq = __int_as_float(m.y);
            acc.x = fmaf(wq, v.x, acc.x); acc.y = fmaf(wq, v.y, acc.y);
            acc.z = fmaf(wq, v.z, acc.z); acc.w = fmaf(wq, v.w, acc.w);
        }
        // combine the 8 edge groups (lanes differing in bits 3,4,5)
        #pragma unroll
        for (int m = 8; m <= 32; m <<= 1) {
            acc.x += __shfl_xor(acc.x, m);
            acc.y += __shfl_xor(acc.y, m);
            acc.z += __shfl_xor(acc.z, m);
            acc.w += __shfl_xor(acc.w, m);
        }
        if (eg == 0) {
            float di2 = di * di;
            float4 bb = *(const float4*)&b2[j4];
            float4 r;
            r.x = fmaxf(fmaf(di2, selfv.x, acc.x) + bb.x, 0.f);
            r.y = fmaxf(fmaf(di2, selfv.y, acc.y) + bb.y, 0.f);
            r.z = fmaxf(fmaf(di2, selfv.z, acc.z) + bb.z, 0.f);
            r.w = fmaxf(fmaf(di2, selfv.w, acc.w) + bb.w, 0.f);
            *(float4*)&smax[w][j4] = r;
        }
    }
    __syncthreads();
    const int t = threadIdx.x;
    if (t < 32) {
        int b0 = sb[0], b1_ = sb[1], b2_ = sb[2], b3_ = sb[3];
        if (b0 >= 0 && b0 == b1_ && b0 == b2_ && b0 == b3_) {
            float v = fmaxf(fmaxf(smax[0][t], smax[1][t]), fmaxf(smax[2][t], smax[3][t]));
            atomicMax(&pooled[b0 * 32 + t], __float_as_uint(v));
        } else {
            #pragma unroll
            for (int ww = 0; ww < 4; ++ww) {
                if (sb[ww] >= 0)
                    atomicMax(&pooled[sb[ww] * 32 + t], __float_as_uint(smax[ww][t]));
            }
        }
    }
}

// ---------------- final: out[64][4] = pooled[64][32] @ Wlin[32][4] + blin ----------------
__global__ __launch_bounds__(NTHREADS) void final_kernel(const float* __restrict__ pooled,
                                                         const float* __restrict__ Wlin,
                                                         const float* __restrict__ blin,
                                                         float* __restrict__ out) {
    int t = threadIdx.x;  // 256 = 64 graphs * 4 cols
    int g = t >> 2, c = t & 3;
    float s = blin[c];
    #pragma unroll
    for (int j = 0; j < 32; ++j) s += pooled[g * 32 + j] * Wlin[j * 4 + c];
    out[g * 4 + c] = s;
}

extern "C" void kernel_launch(void* const* d_in, const int* in_sizes, int n_in,
                              void* d_out, int out_size, void* d_ws, size_t ws_size,
                              hipStream_t stream) {
    const float* x     = (const float*)d_in[0];
    const int*   ei    = (const int*)d_in[1];
    const float* ew    = (const float*)d_in[2];
    const int*   batch = (const int*)d_in[3];
    const float* W1    = (const float*)d_in[4];
    const float* b1    = (const float*)d_in[5];
    const float* W2    = (const float*)d_in[6];
    const float* b2    = (const float*)d_in[7];
    const float* Wlin  = (const float*)d_in[8];
    const float* blin  = (const float*)d_in[9];
    float* out = (float*)d_out;

    const int E = in_sizes[2];   // 3200000
    const int n = in_sizes[3];   // 100000
    const int* src = ei;
    const int* dst = ei + E;

    const int nchunks = (n + SCAN_CHUNK - 1) / SCAN_CHUNK;  // 98

    // workspace layout (4-byte units)
    auto al = [](size_t v) { return (v + 63) & ~(size_t)63; };
    float* ws = (float*)d_ws;
    size_t off = 0;
    float* deg     = ws + off; off += al(n);            // becomes dinv in place
    int*   cnt     = (int*)(ws + off); off += al(n);
    int*   rowptr  = (int*)(ws + off); off += al(n + 1);
    int*   rowfill = (int*)(ws + off); off += al(n + 1);
    int*   bsum    = (int*)(ws + off); off += al(256);
    int2*  meta    = (int2*)(ws + off); off += al((size_t)E * 2);
    float* h1      = ws + off; off += al((size_t)n * 64);   // reused as h2
    float* y1      = ws + off; off += al((size_t)n * 64);
    float* pooled  = ws + off; off += al(64 * 32);
    float* h2 = h1;  // h1 dead after agg1; gemm2 overwrites with h2

    hipMemsetAsync(cnt, 0, (size_t)n * sizeof(int), stream);
    hipMemsetAsync(pooled, 0, 64 * 32 * sizeof(float), stream);

    // degree + histogram + dinv
    deg_init_kernel<<<(n + 255) / 256, NTHREADS, 0, stream>>>(deg, n);
    hist_kernel<<<(E + 255) / 256, NTHREADS, 0, stream>>>(dst, ew, cnt, deg, E);
    dinv_kernel<<<(n + 255) / 256, NTHREADS, 0, stream>>>(deg, n);

    // rowptr = exclusive_scan(cnt)
    scan1_kernel<<<nchunks, NTHREADS, 0, stream>>>(cnt, rowptr, bsum, n);
    scan2_kernel<<<1, NTHREADS, 0, stream>>>(bsum, nchunks);
    scan3_kernel<<<(n + 255) / 256, NTHREADS, 0, stream>>>(rowptr, bsum, n, E);

    // slot-allocation copy, then scatter edges (pre-scaled norm weights)
    hipMemcpyAsync(rowfill, rowptr, (size_t)n * sizeof(int), hipMemcpyDeviceToDevice, stream);
    scatter_kernel<<<(E + 255) / 256, NTHREADS, 0, stream>>>(src, dst, ew, deg, rowfill, meta, E);

    // layer 1
    gemm1_kernel<<<(n + 63) / 64, NTHREADS, 0, stream>>>(x, W1, h1, n);
    agg1_csr_kernel<<<(n + 3) / 4, NTHREADS, 0, stream>>>(rowptr, meta, h1, deg, b1, y1, n);

    // layer 2
    gemm2_kernel<<<(n + 63) / 64, NTHREADS, 0, stream>>>(y1, W2, h2, n);
    agg2_csr_pool_kernel<<<(n + 3) / 4, NTHREADS, 0, stream>>>(
        rowptr, meta, h2, deg, b2, batch, (unsigned int*)pooled, n);

    final_kernel<<<1, NTHREADS, 0, stream>>>(pooled, Wlin, blin, out);
}

// Round 4
// 751.701 us; speedup vs baseline: 2.2424x; 1.2319x over previous
//
#include <hip/hip_runtime.h>
#include <hip/hip_bf16.h>

// GCN: 2x GCNConv (sym-norm, self-loops) + ReLU, segment_max pool, linear.
// N=100000, E=3200000, G=64, IN=256, H1=64, H2=32. All fp32.
// CSR build: ONE u64 atomic per edge (packed cnt|fixedpoint-deg, returned old
// value = slot ticket), scan, then atomic-free scatter. Aggregations are
// wave-per-node gathers with multi-way edge split + shfl combine.

#define NTHREADS 256
#define SCAN_CHUNK 1024
#define DEGMASK ((1ULL << 40) - 1)

// ---- histogram: one packed atomic per edge; old count = CSR ticket ----
__global__ __launch_bounds__(NTHREADS) void hist_kernel(const int* __restrict__ dst,
                                                        const float* __restrict__ ew,
                                                        unsigned long long* __restrict__ packed,
                                                        int* __restrict__ ticket, int nE) {
    int e = blockIdx.x * NTHREADS + threadIdx.x;
    if (e < nE) {
        int d = dst[e];
        unsigned long long add = (1ULL << 40) | (unsigned long long)(ew[e] * 4294967296.0f);
        unsigned long long old = atomicAdd(&packed[d], add);
        ticket[e] = (int)(old >> 40);
    }
}

// ---- dinv: deg = 1 (self loop) + fixed-point sum ----
__global__ __launch_bounds__(NTHREADS) void dinv_kernel(const unsigned long long* __restrict__ packed,
                                                        float* __restrict__ dinv, int n) {
    int i = blockIdx.x * NTHREADS + threadIdx.x;
    if (i < n) {
        double deg = 1.0 + (double)(packed[i] & DEGMASK) * (1.0 / 4294967296.0);
        dinv[i] = rsqrtf((float)deg);
    }
}

// ---- exclusive scan of counts (bits 40+ of packed) -> rowptr ----
__global__ __launch_bounds__(NTHREADS) void scan1_kernel(const unsigned long long* __restrict__ packed,
                                                         int* __restrict__ rowptr,
                                                         int* __restrict__ bsum, int n) {
    __shared__ int tmp[NTHREADS];
    const int base = blockIdx.x * SCAN_CHUNK;
    const int t = threadIdx.x;
    int v[4];
    #pragma unroll
    for (int k = 0; k < 4; ++k) {
        int i = base + t * 4 + k;
        v[k] = (i < n) ? (int)(packed[i] >> 40) : 0;
    }
    int s = v[0] + v[1] + v[2] + v[3];
    tmp[t] = s;
    __syncthreads();
    for (int off = 1; off < NTHREADS; off <<= 1) {
        int val = (t >= off) ? tmp[t - off] : 0;
        __syncthreads();
        tmp[t] += val;
        __syncthreads();
    }
    int excl = tmp[t] - s;
    if (t == NTHREADS - 1) bsum[blockIdx.x] = tmp[NTHREADS - 1];
    int run = excl;
    #pragma unroll
    for (int k = 0; k < 4; ++k) {
        int i = base + t * 4 + k;
        if (i < n) rowptr[i] = run;
        run += v[k];
    }
}

__global__ __launch_bounds__(NTHREADS) void scan2_kernel(int* __restrict__ bsum, int nb) {
    __shared__ int tmp[NTHREADS];
    int t = threadIdx.x;
    int v = (t < nb) ? bsum[t] : 0;
    tmp[t] = v;
    __syncthreads();
    for (int off = 1; off < NTHREADS; off <<= 1) {
        int val = (t >= off) ? tmp[t - off] : 0;
        __syncthreads();
        tmp[t] += val;
        __syncthreads();
    }
    if (t < nb) bsum[t] = tmp[t] - v;  // exclusive
}

__global__ __launch_bounds__(NTHREADS) void scan3_kernel(int* __restrict__ rowptr,
                                                         const int* __restrict__ bsum,
                                                         int n, int E) {
    int i = blockIdx.x * NTHREADS + threadIdx.x;
    if (i < n) rowptr[i] += bsum[i / SCAN_CHUNK];
    if (i == 0) rowptr[n] = E;
}

// ---- scatter edges into CSR slots (NO atomics; ticket from hist) ----
__global__ __launch_bounds__(NTHREADS) void scatter_kernel(const int* __restrict__ src,
                                                           const int* __restrict__ dst,
                                                           const float* __restrict__ ew,
                                                           const float* __restrict__ dinv,
                                                           const int* __restrict__ rowptr,
                                                           const int* __restrict__ ticket,
                                                           int2* __restrict__ meta, int nE) {
    int e = blockIdx.x * NTHREADS + threadIdx.x;
    if (e >= nE) return;
    int s = src[e], d = dst[e];
    int pos = rowptr[d] + ticket[e];
    float w = dinv[s] * ew[e] * dinv[d];
    meta[pos] = make_int2(s, __float_as_int(w));
}

// ---------------- GEMM1: h1[n][64] = x[n][256] @ W1[256][64] ----------------
__global__ __launch_bounds__(NTHREADS) void gemm1_kernel(const float* __restrict__ x,
                                                         const float* __restrict__ W,
                                                         float* __restrict__ h, int n) {
    __shared__ float xT[32][68];
    __shared__ float ws[32][64];
    const int t = threadIdx.x;
    const int row0 = blockIdx.x * 64;
    const int tc4 = (t & 15) * 4;
    const int tr4 = (t >> 4) * 4;
    float acc[4][4] = {};

    const int tx = t & 31;
    const int ty = t >> 5;

    for (int kb = 0; kb < 256; kb += 32) {
        #pragma unroll
        for (int rp = 0; rp < 8; ++rp) {
            int r = ty + rp * 8;
            int grow = row0 + r;
            float v = (grow < n) ? x[(size_t)grow * 256 + kb + tx] : 0.0f;
            xT[tx][r] = v;
        }
        #pragma unroll
        for (int p = 0; p < 8; ++p) {
            int idx = p * 256 + t;
            ws[idx >> 6][idx & 63] = W[(size_t)(kb + (idx >> 6)) * 64 + (idx & 63)];
        }
        __syncthreads();
        #pragma unroll
        for (int kk = 0; kk < 32; ++kk) {
            float4 xv = *(const float4*)&xT[kk][tr4];
            float4 wv = *(const float4*)&ws[kk][tc4];
            acc[0][0] += xv.x * wv.x; acc[0][1] += xv.x * wv.y; acc[0][2] += xv.x * wv.z; acc[0][3] += xv.x * wv.w;
            acc[1][0] += xv.y * wv.x; acc[1][1] += xv.y * wv.y; acc[1][2] += xv.y * wv.z; acc[1][3] += xv.y * wv.w;
            acc[2][0] += xv.z * wv.x; acc[2][1] += xv.z * wv.y; acc[2][2] += xv.z * wv.z; acc[2][3] += xv.z * wv.w;
            acc[3][0] += xv.w * wv.x; acc[3][1] += xv.w * wv.y; acc[3][2] += xv.w * wv.z; acc[3][3] += xv.w * wv.w;
        }
        __syncthreads();
    }
    #pragma unroll
    for (int r = 0; r < 4; ++r) {
        int grow = row0 + tr4 + r;
        if (grow < n) {
            float4 o = make_float4(acc[r][0], acc[r][1], acc[r][2], acc[r][3]);
            *(float4*)&h[(size_t)grow * 64 + tc4] = o;
        }
    }
}

// ---- agg1: wave-per-node, 16 lanes x float4, 4-way edge split ----
__global__ __launch_bounds__(NTHREADS) void agg1_csr_kernel(const int* __restrict__ rowptr,
                                                            const int2* __restrict__ meta,
                                                            const float* __restrict__ h1,
                                                            const float* __restrict__ dinv,
                                                            const float* __restrict__ b1,
                                                            float* __restrict__ y1, int n) {
    const int wid = (blockIdx.x * NTHREADS + threadIdx.x) >> 6;  // node
    if (wid >= n) return;
    const int l = threadIdx.x & 63;
    const int fg = l & 15, eg = l >> 4;
    const int j4 = fg * 4;
    const int beg = rowptr[wid], end = rowptr[wid + 1];
    const float di = dinv[wid];
    const float4 selfv = *(const float4*)&h1[(size_t)wid * 64 + j4];

    float4 acc = make_float4(0.f, 0.f, 0.f, 0.f);
    int k = beg + eg;
    for (; k + 4 < end; k += 8) {
        int2 m0 = meta[k];
        int2 m1 = meta[k + 4];
        float4 v0 = *(const float4*)&h1[(size_t)m0.x * 64 + j4];
        float4 v1 = *(const float4*)&h1[(size_t)m1.x * 64 + j4];
        float w0 = __int_as_float(m0.y), w1 = __int_as_float(m1.y);
        acc.x = fmaf(w0, v0.x, acc.x); acc.y = fmaf(w0, v0.y, acc.y);
        acc.z = fmaf(w0, v0.z, acc.z); acc.w = fmaf(w0, v0.w, acc.w);
        acc.x = fmaf(w1, v1.x, acc.x); acc.y = fmaf(w1, v1.y, acc.y);
        acc.z = fmaf(w1, v1.z, acc.z); acc.w = fmaf(w1, v1.w, acc.w);
    }
    if (k < end) {
        int2 m = meta[k];
        float4 v = *(const float4*)&h1[(size_t)m.x * 64 + j4];
        float w = __int_as_float(m.y);
        acc.x = fmaf(w, v.x, acc.x); acc.y = fmaf(w, v.y, acc.y);
        acc.z = fmaf(w, v.z, acc.z); acc.w = fmaf(w, v.w, acc.w);
    }
    #pragma unroll
    for (int m = 16; m <= 32; m <<= 1) {
        acc.x += __shfl_xor(acc.x, m);
        acc.y += __shfl_xor(acc.y, m);
        acc.z += __shfl_xor(acc.z, m);
        acc.w += __shfl_xor(acc.w, m);
    }
    if (eg == 0) {
        float di2 = di * di;
        float4 bb = *(const float4*)&b1[j4];
        float4 r;
        r.x = fmaxf(fmaf(di2, selfv.x, acc.x) + bb.x, 0.f);
        r.y = fmaxf(fmaf(di2, selfv.y, acc.y) + bb.y, 0.f);
        r.z = fmaxf(fmaf(di2, selfv.z, acc.z) + bb.z, 0.f);
        r.w = fmaxf(fmaf(di2, selfv.w, acc.w) + bb.w, 0.f);
        *(float4*)&y1[(size_t)wid * 64 + j4] = r;
    }
}

// ---------------- GEMM2: h2[n][32] = y1[n][64] @ W2[64][32] ----------------
__global__ __launch_bounds__(NTHREADS) void gemm2_kernel(const float* __restrict__ y1,
                                                         const float* __restrict__ W,
                                                         float* __restrict__ h, int n) {
    __shared__ float xT[64][68];
    __shared__ float ws[64][32];
    const int t = threadIdx.x;
    const int row0 = blockIdx.x * 64;
    const int tc2 = (t & 15) * 2;
    const int tr4 = (t >> 4) * 4;
    float acc[4][2] = {};

    const int tx = t & 63;
    const int ty = t >> 6;
    #pragma unroll
    for (int rp = 0; rp < 16; ++rp) {
        int r = ty * 16 + rp;
        int grow = row0 + r;
        float v = (grow < n) ? y1[(size_t)grow * 64 + tx] : 0.0f;
        xT[tx][r] = v;
    }
    #pragma unroll
    for (int p = 0; p < 8; ++p) {
        int idx = p * 256 + t;
        ws[idx >> 5][idx & 31] = W[idx];
    }
    __syncthreads();
    #pragma unroll
    for (int kk = 0; kk < 64; ++kk) {
        float4 xv = *(const float4*)&xT[kk][tr4];
        float2 wv = *(const float2*)&ws[kk][tc2];
        acc[0][0] += xv.x * wv.x; acc[0][1] += xv.x * wv.y;
        acc[1][0] += xv.y * wv.x; acc[1][1] += xv.y * wv.y;
        acc[2][0] += xv.z * wv.x; acc[2][1] += xv.z * wv.y;
        acc[3][0] += xv.w * wv.x; acc[3][1] += xv.w * wv.y;
    }
    #pragma unroll
    for (int r = 0; r < 4; ++r) {
        int grow = row0 + tr4 + r;
        if (grow < n) {
            float2 o = make_float2(acc[r][0], acc[r][1]);
            *(float2*)&h[(size_t)grow * 32 + tc2] = o;
        }
    }
}

// ---- agg2: wave-per-node, 8 lanes x float4, 8-way edge split, LDS pool ----
__global__ __launch_bounds__(NTHREADS) void agg2_csr_pool_kernel(const int* __restrict__ rowptr,
                                                                 const int2* __restrict__ meta,
                                                                 const float* __restrict__ h2,
                                                                 const float* __restrict__ dinv,
                                                                 const float* __restrict__ b2,
                                                                 const int* __restrict__ batch,
                                                                 unsigned int* __restrict__ pooled,
                                                                 int n) {
    __shared__ float smax[4][32];
    __shared__ int sb[4];
    const int w = threadIdx.x >> 6;            // wave in block
    const int l = threadIdx.x & 63;
    const int node = blockIdx.x * 4 + w;
    const bool active = node < n;
    const int fg = l & 7, eg = l >> 3;
    const int j4 = fg * 4;

    if (l == 0) sb[w] = active ? batch[node] : -1;

    if (active) {
        const int beg = rowptr[node], end = rowptr[node + 1];
        const float di = dinv[node];
        const float4 selfv = *(const float4*)&h2[(size_t)node * 32 + j4];

        float4 acc = make_float4(0.f, 0.f, 0.f, 0.f);
        int k = beg + eg;
        for (; k + 8 < end; k += 16) {
            int2 m0 = meta[k];
            int2 m1 = meta[k + 8];
            float4 v0 = *(const float4*)&h2[(size_t)m0.x * 32 + j4];
            float4 v1 = *(const float4*)&h2[(size_t)m1.x * 32 + j4];
            float w0 = __int_as_float(m0.y), w1 = __int_as_float(m1.y);
            acc.x = fmaf(w0, v0.x, acc.x); acc.y = fmaf(w0, v0.y, acc.y);
            acc.z = fmaf(w0, v0.z, acc.z); acc.w = fmaf(w0, v0.w, acc.w);
            acc.x = fmaf(w1, v1.x, acc.x); acc.y = fmaf(w1, v1.y, acc.y);
            acc.z = fmaf(w1, v1.z, acc.z); acc.w = fmaf(w1, v1.w, acc.w);
        }
        if (k < end) {
            int2 m = meta[k];
            float4 v = *(const float4*)&h2[(size_t)m.x * 32 + j4];
            float wq = __int_as_float(m.y);
            acc.x = fmaf(wq, v.x, acc.x); acc.y = fmaf(wq, v.y, acc.y);
            acc.z = fmaf(wq, v.z, acc.z); acc.w = fmaf(wq, v.w, acc.w);
        }
        #pragma unroll
        for (int m = 8; m <= 32; m <<= 1) {
            acc.x += __shfl_xor(acc.x, m);
            acc.y += __shfl_xor(acc.y, m);
            acc.z += __shfl_xor(acc.z, m);
            acc.w += __shfl_xor(acc.w, m);
        }
        if (eg == 0) {
            float di2 = di * di;
            float4 bb = *(const float4*)&b2[j4];
            float4 r;
            r.x = fmaxf(fmaf(di2, selfv.x, acc.x) + bb.x, 0.f);
            r.y = fmaxf(fmaf(di2, selfv.y, acc.y) + bb.y, 0.f);
            r.z = fmaxf(fmaf(di2, selfv.z, acc.z) + bb.z, 0.f);
            r.w = fmaxf(fmaf(di2, selfv.w, acc.w) + bb.w, 0.f);
            *(float4*)&smax[w][j4] = r;
        }
    }
    __syncthreads();
    const int t = threadIdx.x;
    if (t < 32) {
        int b0 = sb[0], b1_ = sb[1], b2_ = sb[2], b3_ = sb[3];
        if (b0 >= 0 && b0 == b1_ && b0 == b2_ && b0 == b3_) {
            float v = fmaxf(fmaxf(smax[0][t], smax[1][t]), fmaxf(smax[2][t], smax[3][t]));
            atomicMax(&pooled[b0 * 32 + t], __float_as_uint(v));
        } else {
            #pragma unroll
            for (int ww = 0; ww < 4; ++ww) {
                if (sb[ww] >= 0)
                    atomicMax(&pooled[sb[ww] * 32 + t], __float_as_uint(smax[ww][t]));
            }
        }
    }
}

// ---------------- final: out[64][4] = pooled[64][32] @ Wlin[32][4] + blin ----------------
__global__ __launch_bounds__(NTHREADS) void final_kernel(const float* __restrict__ pooled,
                                                         const float* __restrict__ Wlin,
                                                         const float* __restrict__ blin,
                                                         float* __restrict__ out) {
    int t = threadIdx.x;  // 256 = 64 graphs * 4 cols
    int g = t >> 2, c = t & 3;
    float s = blin[c];
    #pragma unroll
    for (int j = 0; j < 32; ++j) s += pooled[g * 32 + j] * Wlin[j * 4 + c];
    out[g * 4 + c] = s;
}

extern "C" void kernel_launch(void* const* d_in, const int* in_sizes, int n_in,
                              void* d_out, int out_size, void* d_ws, size_t ws_size,
                              hipStream_t stream) {
    const float* x     = (const float*)d_in[0];
    const int*   ei    = (const int*)d_in[1];
    const float* ew    = (const float*)d_in[2];
    const int*   batch = (const int*)d_in[3];
    const float* W1    = (const float*)d_in[4];
    const float* b1    = (const float*)d_in[5];
    const float* W2    = (const float*)d_in[6];
    const float* b2    = (const float*)d_in[7];
    const float* Wlin  = (const float*)d_in[8];
    const float* blin  = (const float*)d_in[9];
    float* out = (float*)d_out;

    const int E = in_sizes[2];   // 3200000
    const int n = in_sizes[3];   // 100000
    const int* src = ei;
    const int* dst = ei + E;

    const int nchunks = (n + SCAN_CHUNK - 1) / SCAN_CHUNK;  // 98

    // workspace layout (4-byte units), 256B-aligned chunks
    auto al = [](size_t v) { return (v + 63) & ~(size_t)63; };
    float* ws = (float*)d_ws;
    size_t off = 0;
    unsigned long long* packed = (unsigned long long*)(ws + off); off += al((size_t)n * 2);
    float* dinv    = ws + off; off += al(n);
    int*   ticket  = (int*)(ws + off); off += al(E);
    int*   rowptr  = (int*)(ws + off); off += al(n + 1);
    int*   bsum    = (int*)(ws + off); off += al(256);
    int2*  meta    = (int2*)(ws + off); off += al((size_t)E * 2);
    float* h1      = ws + off; off += al((size_t)n * 64);   // reused as h2
    float* y1      = ws + off; off += al((size_t)n * 64);
    float* pooled  = ws + off; off += al(64 * 32);
    float* h2 = h1;  // h1 dead after agg1; gemm2 overwrites with h2

    hipMemsetAsync(packed, 0, (size_t)n * sizeof(unsigned long long), stream);
    hipMemsetAsync(pooled, 0, 64 * 32 * sizeof(float), stream);

    // histogram (1 packed atomic/edge, ticket out) + dinv
    hist_kernel<<<(E + 255) / 256, NTHREADS, 0, stream>>>(dst, ew, packed, ticket, E);
    dinv_kernel<<<(n + 255) / 256, NTHREADS, 0, stream>>>(packed, dinv, n);

    // rowptr = exclusive_scan(cnt)
    scan1_kernel<<<nchunks, NTHREADS, 0, stream>>>(packed, rowptr, bsum, n);
    scan2_kernel<<<1, NTHREADS, 0, stream>>>(bsum, nchunks);
    scan3_kernel<<<(n + 255) / 256, NTHREADS, 0, stream>>>(rowptr, bsum, n, E);

    // atomic-free scatter (pre-scaled norm weights)
    scatter_kernel<<<(E + 255) / 256, NTHREADS, 0, stream>>>(src, dst, ew, dinv, rowptr, ticket, meta, E);

    // layer 1
    gemm1_kernel<<<(n + 63) / 64, NTHREADS, 0, stream>>>(x, W1, h1, n);
    agg1_csr_kernel<<<(n + 3) / 4, NTHREADS, 0, stream>>>(rowptr, meta, h1, dinv, b1, y1, n);

    // layer 2
    gemm2_kernel<<<(n + 63) / 64, NTHREADS, 0, stream>>>(y1, W2, h2, n);
    agg2_csr_pool_kernel<<<(n + 3) / 4, NTHREADS, 0, stream>>>(
        rowptr, meta, h2, dinv, b2, batch, (unsigned int*)pooled, n);

    final_kernel<<<1, NTHREADS, 0, stream>>>(pooled, Wlin, blin, out);
}

// Round 5
// 725.603 us; speedup vs baseline: 2.3231x; 1.0360x over previous
//
#include <hip/hip_runtime.h>
#include <hip/hip_bf16.h>

// GCN: 2x GCNConv (sym-norm, self-loops) + ReLU, segment_max pool, linear.
// N=100000, E=3200000, G=64, IN=256, H1=64, H2=32. All fp32.
// CSR build: ONE u64 atomic per edge (packed cnt|fixedpoint-deg, old value =
// slot ticket), scan, atomic-free scatter of 4B-packed (src<<15|ew15) meta.
// GEMMs write g = dinv*.(X@W); aggs compute relu(dinv_d*(sum ew*g[src] + g[d]) + b).

#define NTHREADS 256
#define SCAN_CHUNK 1024
#define DEGMASK ((1ULL << 40) - 1)

// ---- histogram: one packed atomic per edge; old count = CSR ticket ----
__global__ __launch_bounds__(NTHREADS) void hist_kernel(const int* __restrict__ dst,
                                                        const float* __restrict__ ew,
                                                        unsigned long long* __restrict__ packed,
                                                        int* __restrict__ ticket, int nE) {
    int e = blockIdx.x * NTHREADS + threadIdx.x;
    if (e < nE) {
        int d = dst[e];
        unsigned long long add = (1ULL << 40) | (unsigned long long)(ew[e] * 4294967296.0f);
        unsigned long long old = atomicAdd(&packed[d], add);
        ticket[e] = (int)(old >> 40);
    }
}

// ---- dinv: deg = 1 (self loop) + fixed-point sum ----
__global__ __launch_bounds__(NTHREADS) void dinv_kernel(const unsigned long long* __restrict__ packed,
                                                        float* __restrict__ dinv, int n) {
    int i = blockIdx.x * NTHREADS + threadIdx.x;
    if (i < n) {
        double deg = 1.0 + (double)(packed[i] & DEGMASK) * (1.0 / 4294967296.0);
        dinv[i] = rsqrtf((float)deg);
    }
}

// ---- exclusive scan of counts (bits 40+ of packed) -> rowptr ----
__global__ __launch_bounds__(NTHREADS) void scan1_kernel(const unsigned long long* __restrict__ packed,
                                                         int* __restrict__ rowptr,
                                                         int* __restrict__ bsum, int n) {
    __shared__ int tmp[NTHREADS];
    const int base = blockIdx.x * SCAN_CHUNK;
    const int t = threadIdx.x;
    int v[4];
    #pragma unroll
    for (int k = 0; k < 4; ++k) {
        int i = base + t * 4 + k;
        v[k] = (i < n) ? (int)(packed[i] >> 40) : 0;
    }
    int s = v[0] + v[1] + v[2] + v[3];
    tmp[t] = s;
    __syncthreads();
    for (int off = 1; off < NTHREADS; off <<= 1) {
        int val = (t >= off) ? tmp[t - off] : 0;
        __syncthreads();
        tmp[t] += val;
        __syncthreads();
    }
    int excl = tmp[t] - s;
    if (t == NTHREADS - 1) bsum[blockIdx.x] = tmp[NTHREADS - 1];
    int run = excl;
    #pragma unroll
    for (int k = 0; k < 4; ++k) {
        int i = base + t * 4 + k;
        if (i < n) rowptr[i] = run;
        run += v[k];
    }
}

__global__ __launch_bounds__(NTHREADS) void scan2_kernel(int* __restrict__ bsum, int nb) {
    __shared__ int tmp[NTHREADS];
    int t = threadIdx.x;
    int v = (t < nb) ? bsum[t] : 0;
    tmp[t] = v;
    __syncthreads();
    for (int off = 1; off < NTHREADS; off <<= 1) {
        int val = (t >= off) ? tmp[t - off] : 0;
        __syncthreads();
        tmp[t] += val;
        __syncthreads();
    }
    if (t < nb) bsum[t] = tmp[t] - v;  // exclusive
}

__global__ __launch_bounds__(NTHREADS) void scan3_kernel(int* __restrict__ rowptr,
                                                         const int* __restrict__ bsum,
                                                         int n, int E) {
    int i = blockIdx.x * NTHREADS + threadIdx.x;
    if (i < n) rowptr[i] += bsum[i / SCAN_CHUNK];
    if (i == 0) rowptr[n] = E;
}

// ---- scatter edges into CSR slots (NO atomics; ticket from hist) ----
// meta = (src << 15) | round(ew * 32768) clamped to 15 bits.
__global__ __launch_bounds__(NTHREADS) void scatter_kernel(const int* __restrict__ src,
                                                           const int* __restrict__ dst,
                                                           const float* __restrict__ ew,
                                                           const int* __restrict__ rowptr,
                                                           const int* __restrict__ ticket,
                                                           unsigned int* __restrict__ meta, int nE) {
    int e = blockIdx.x * NTHREADS + threadIdx.x;
    if (e >= nE) return;
    int s = src[e], d = dst[e];
    int pos = rowptr[d] + ticket[e];
    unsigned int q = (unsigned int)(ew[e] * 32768.0f + 0.5f);
    q = q > 32767u ? 32767u : q;
    meta[pos] = ((unsigned int)s << 15) | q;
}

// ---- GEMM1: g1[n][64] = dinv[row] * (x[n][256] @ W1[256][64]) ----
__global__ __launch_bounds__(NTHREADS) void gemm1_kernel(const float* __restrict__ x,
                                                         const float* __restrict__ W,
                                                         const float* __restrict__ dinv,
                                                         float* __restrict__ g, int n) {
    __shared__ float xT[32][68];
    __shared__ float ws[32][64];
    const int t = threadIdx.x;
    const int row0 = blockIdx.x * 64;
    const int tc4 = (t & 15) * 4;
    const int tr4 = (t >> 4) * 4;
    float acc[4][4] = {};

    const int tx = t & 31;
    const int ty = t >> 5;

    for (int kb = 0; kb < 256; kb += 32) {
        #pragma unroll
        for (int rp = 0; rp < 8; ++rp) {
            int r = ty + rp * 8;
            int grow = row0 + r;
            float v = (grow < n) ? x[(size_t)grow * 256 + kb + tx] : 0.0f;
            xT[tx][r] = v;
        }
        #pragma unroll
        for (int p = 0; p < 8; ++p) {
            int idx = p * 256 + t;
            ws[idx >> 6][idx & 63] = W[(size_t)(kb + (idx >> 6)) * 64 + (idx & 63)];
        }
        __syncthreads();
        #pragma unroll
        for (int kk = 0; kk < 32; ++kk) {
            float4 xv = *(const float4*)&xT[kk][tr4];
            float4 wv = *(const float4*)&ws[kk][tc4];
            acc[0][0] += xv.x * wv.x; acc[0][1] += xv.x * wv.y; acc[0][2] += xv.x * wv.z; acc[0][3] += xv.x * wv.w;
            acc[1][0] += xv.y * wv.x; acc[1][1] += xv.y * wv.y; acc[1][2] += xv.y * wv.z; acc[1][3] += xv.y * wv.w;
            acc[2][0] += xv.z * wv.x; acc[2][1] += xv.z * wv.y; acc[2][2] += xv.z * wv.z; acc[2][3] += xv.z * wv.w;
            acc[3][0] += xv.w * wv.x; acc[3][1] += xv.w * wv.y; acc[3][2] += xv.w * wv.z; acc[3][3] += xv.w * wv.w;
        }
        __syncthreads();
    }
    #pragma unroll
    for (int r = 0; r < 4; ++r) {
        int grow = row0 + tr4 + r;
        if (grow < n) {
            float di = dinv[grow];
            float4 o = make_float4(di * acc[r][0], di * acc[r][1], di * acc[r][2], di * acc[r][3]);
            *(float4*)&g[(size_t)grow * 64 + tc4] = o;
        }
    }
}

// ---- agg1: wave-per-node, 16 lanes x float4, 4-way edge split ----
// y1 = relu(dinv_d * (sum ew*g1[src] + g1[d]) + b1)
__global__ __launch_bounds__(NTHREADS) void agg1_csr_kernel(const int* __restrict__ rowptr,
                                                            const unsigned int* __restrict__ meta,
                                                            const float* __restrict__ g1,
                                                            const float* __restrict__ dinv,
                                                            const float* __restrict__ b1,
                                                            float* __restrict__ y1, int n) {
    const int wid = (blockIdx.x * NTHREADS + threadIdx.x) >> 6;  // node
    if (wid >= n) return;
    const int l = threadIdx.x & 63;
    const int fg = l & 15, eg = l >> 4;
    const int j4 = fg * 4;
    const int beg = rowptr[wid], end = rowptr[wid + 1];
    const float di = dinv[wid];
    const float4 selfv = *(const float4*)&g1[(size_t)wid * 64 + j4];

    float4 acc = make_float4(0.f, 0.f, 0.f, 0.f);
    int k = beg + eg;
    for (; k + 4 < end; k += 8) {
        unsigned int m0 = meta[k];
        unsigned int m1 = meta[k + 4];
        float4 v0 = *(const float4*)&g1[(size_t)(m0 >> 15) * 64 + j4];
        float4 v1 = *(const float4*)&g1[(size_t)(m1 >> 15) * 64 + j4];
        float w0 = (float)(m0 & 32767u) * (1.0f / 32768.0f);
        float w1 = (float)(m1 & 32767u) * (1.0f / 32768.0f);
        acc.x = fmaf(w0, v0.x, acc.x); acc.y = fmaf(w0, v0.y, acc.y);
        acc.z = fmaf(w0, v0.z, acc.z); acc.w = fmaf(w0, v0.w, acc.w);
        acc.x = fmaf(w1, v1.x, acc.x); acc.y = fmaf(w1, v1.y, acc.y);
        acc.z = fmaf(w1, v1.z, acc.z); acc.w = fmaf(w1, v1.w, acc.w);
    }
    if (k < end) {
        unsigned int m = meta[k];
        float4 v = *(const float4*)&g1[(size_t)(m >> 15) * 64 + j4];
        float w = (float)(m & 32767u) * (1.0f / 32768.0f);
        acc.x = fmaf(w, v.x, acc.x); acc.y = fmaf(w, v.y, acc.y);
        acc.z = fmaf(w, v.z, acc.z); acc.w = fmaf(w, v.w, acc.w);
    }
    #pragma unroll
    for (int m = 16; m <= 32; m <<= 1) {
        acc.x += __shfl_xor(acc.x, m);
        acc.y += __shfl_xor(acc.y, m);
        acc.z += __shfl_xor(acc.z, m);
        acc.w += __shfl_xor(acc.w, m);
    }
    if (eg == 0) {
        float4 bb = *(const float4*)&b1[j4];
        float4 r;
        r.x = fmaxf(fmaf(di, acc.x + selfv.x, bb.x), 0.f);
        r.y = fmaxf(fmaf(di, acc.y + selfv.y, bb.y), 0.f);
        r.z = fmaxf(fmaf(di, acc.z + selfv.z, bb.z), 0.f);
        r.w = fmaxf(fmaf(di, acc.w + selfv.w, bb.w), 0.f);
        *(float4*)&y1[(size_t)wid * 64 + j4] = r;
    }
}

// ---- GEMM2: g2[n][32] = dinv[row] * (y1[n][64] @ W2[64][32]) ----
__global__ __launch_bounds__(NTHREADS) void gemm2_kernel(const float* __restrict__ y1,
                                                         const float* __restrict__ W,
                                                         const float* __restrict__ dinv,
                                                         float* __restrict__ g, int n) {
    __shared__ float xT[64][68];
    __shared__ float ws[64][32];
    const int t = threadIdx.x;
    const int row0 = blockIdx.x * 64;
    const int tc2 = (t & 15) * 2;
    const int tr4 = (t >> 4) * 4;
    float acc[4][2] = {};

    const int tx = t & 63;
    const int ty = t >> 6;
    #pragma unroll
    for (int rp = 0; rp < 16; ++rp) {
        int r = ty * 16 + rp;
        int grow = row0 + r;
        float v = (grow < n) ? y1[(size_t)grow * 64 + tx] : 0.0f;
        xT[tx][r] = v;
    }
    #pragma unroll
    for (int p = 0; p < 8; ++p) {
        int idx = p * 256 + t;
        ws[idx >> 5][idx & 31] = W[idx];
    }
    __syncthreads();
    #pragma unroll
    for (int kk = 0; kk < 64; ++kk) {
        float4 xv = *(const float4*)&xT[kk][tr4];
        float2 wv = *(const float2*)&ws[kk][tc2];
        acc[0][0] += xv.x * wv.x; acc[0][1] += xv.x * wv.y;
        acc[1][0] += xv.y * wv.x; acc[1][1] += xv.y * wv.y;
        acc[2][0] += xv.z * wv.x; acc[2][1] += xv.z * wv.y;
        acc[3][0] += xv.w * wv.x; acc[3][1] += xv.w * wv.y;
    }
    #pragma unroll
    for (int r = 0; r < 4; ++r) {
        int grow = row0 + tr4 + r;
        if (grow < n) {
            float di = dinv[grow];
            float2 o = make_float2(di * acc[r][0], di * acc[r][1]);
            *(float2*)&g[(size_t)grow * 32 + tc2] = o;
        }
    }
}

// ---- agg2: wave-per-node, 8 lanes x float4, 8-way edge split, LDS pool ----
__global__ __launch_bounds__(NTHREADS) void agg2_csr_pool_kernel(const int* __restrict__ rowptr,
                                                                 const unsigned int* __restrict__ meta,
                                                                 const float* __restrict__ g2,
                                                                 const float* __restrict__ dinv,
                                                                 const float* __restrict__ b2,
                                                                 const int* __restrict__ batch,
                                                                 unsigned int* __restrict__ pooled,
                                                                 int n) {
    __shared__ float smax[4][32];
    __shared__ int sb[4];
    const int w = threadIdx.x >> 6;            // wave in block
    const int l = threadIdx.x & 63;
    const int node = blockIdx.x * 4 + w;
    const bool active = node < n;
    const int fg = l & 7, eg = l >> 3;
    const int j4 = fg * 4;

    if (l == 0) sb[w] = active ? batch[node] : -1;

    if (active) {
        const int beg = rowptr[node], end = rowptr[node + 1];
        const float di = dinv[node];
        const float4 selfv = *(const float4*)&g2[(size_t)node * 32 + j4];

        float4 acc = make_float4(0.f, 0.f, 0.f, 0.f);
        int k = beg + eg;
        for (; k + 8 < end; k += 16) {
            unsigned int m0 = meta[k];
            unsigned int m1 = meta[k + 8];
            float4 v0 = *(const float4*)&g2[(size_t)(m0 >> 15) * 32 + j4];
            float4 v1 = *(const float4*)&g2[(size_t)(m1 >> 15) * 32 + j4];
            float w0 = (float)(m0 & 32767u) * (1.0f / 32768.0f);
            float w1 = (float)(m1 & 32767u) * (1.0f / 32768.0f);
            acc.x = fmaf(w0, v0.x, acc.x); acc.y = fmaf(w0, v0.y, acc.y);
            acc.z = fmaf(w0, v0.z, acc.z); acc.w = fmaf(w0, v0.w, acc.w);
            acc.x = fmaf(w1, v1.x, acc.x); acc.y = fmaf(w1, v1.y, acc.y);
            acc.z = fmaf(w1, v1.z, acc.z); acc.w = fmaf(w1, v1.w, acc.w);
        }
        if (k < end) {
            unsigned int m = meta[k];
            float4 v = *(const float4*)&g2[(size_t)(m >> 15) * 32 + j4];
            float wq = (float)(m & 32767u) * (1.0f / 32768.0f);
            acc.x = fmaf(wq, v.x, acc.x); acc.y = fmaf(wq, v.y, acc.y);
            acc.z = fmaf(wq, v.z, acc.z); acc.w = fmaf(wq, v.w, acc.w);
        }
        #pragma unroll
        for (int m = 8; m <= 32; m <<= 1) {
            acc.x += __shfl_xor(acc.x, m);
            acc.y += __shfl_xor(acc.y, m);
            acc.z += __shfl_xor(acc.z, m);
            acc.w += __shfl_xor(acc.w, m);
        }
        if (eg == 0) {
            float4 bb = *(const float4*)&b2[j4];
            float4 r;
            r.x = fmaxf(fmaf(di, acc.x + selfv.x, bb.x), 0.f);
            r.y = fmaxf(fmaf(di, acc.y + selfv.y, bb.y), 0.f);
            r.z = fmaxf(fmaf(di, acc.z + selfv.z, bb.z), 0.f);
            r.w = fmaxf(fmaf(di, acc.w + selfv.w, bb.w), 0.f);
            *(float4*)&smax[w][j4] = r;
        }
    }
    __syncthreads();
    const int t = threadIdx.x;
    if (t < 32) {
        int b0 = sb[0], b1_ = sb[1], b2_ = sb[2], b3_ = sb[3];
        if (b0 >= 0 && b0 == b1_ && b0 == b2_ && b0 == b3_) {
            float v = fmaxf(fmaxf(smax[0][t], smax[1][t]), fmaxf(smax[2][t], smax[3][t]));
            atomicMax(&pooled[b0 * 32 + t], __float_as_uint(v));
        } else {
            #pragma unroll
            for (int ww = 0; ww < 4; ++ww) {
                if (sb[ww] >= 0)
                    atomicMax(&pooled[sb[ww] * 32 + t], __float_as_uint(smax[ww][t]));
            }
        }
    }
}

// ---------------- final: out[64][4] = pooled[64][32] @ Wlin[32][4] + blin ----------------
__global__ __launch_bounds__(NTHREADS) void final_kernel(const float* __restrict__ pooled,
                                                         const float* __restrict__ Wlin,
                                                         const float* __restrict__ blin,
                                                         float* __restrict__ out) {
    int t = threadIdx.x;  // 256 = 64 graphs * 4 cols
    int g = t >> 2, c = t & 3;
    float s = blin[c];
    #pragma unroll
    for (int j = 0; j < 32; ++j) s += pooled[g * 32 + j] * Wlin[j * 4 + c];
    out[g * 4 + c] = s;
}

extern "C" void kernel_launch(void* const* d_in, const int* in_sizes, int n_in,
                              void* d_out, int out_size, void* d_ws, size_t ws_size,
                              hipStream_t stream) {
    const float* x     = (const float*)d_in[0];
    const int*   ei    = (const int*)d_in[1];
    const float* ew    = (const float*)d_in[2];
    const int*   batch = (const int*)d_in[3];
    const float* W1    = (const float*)d_in[4];
    const float* b1    = (const float*)d_in[5];
    const float* W2    = (const float*)d_in[6];
    const float* b2    = (const float*)d_in[7];
    const float* Wlin  = (const float*)d_in[8];
    const float* blin  = (const float*)d_in[9];
    float* out = (float*)d_out;

    const int E = in_sizes[2];   // 3200000
    const int n = in_sizes[3];   // 100000
    const int* src = ei;
    const int* dst = ei + E;

    const int nchunks = (n + SCAN_CHUNK - 1) / SCAN_CHUNK;  // 98

    // workspace layout (4-byte units)
    auto al = [](size_t v) { return (v + 63) & ~(size_t)63; };
    float* ws = (float*)d_ws;
    size_t off = 0;
    unsigned long long* packed = (unsigned long long*)(ws + off); off += al((size_t)n * 2);
    float* dinv    = ws + off; off += al(n);
    int*   ticket  = (int*)(ws + off); off += al(E);
    int*   rowptr  = (int*)(ws + off); off += al(n + 1);
    int*   bsum    = (int*)(ws + off); off += al(256);
    unsigned int* meta = (unsigned int*)(ws + off); off += al(E);
    float* g1      = ws + off; off += al((size_t)n * 64);   // reused as g2
    float* y1      = ws + off; off += al((size_t)n * 64);
    float* pooled  = ws + off; off += al(64 * 32);
    float* g2 = g1;  // g1 dead after agg1; gemm2 overwrites with g2

    hipMemsetAsync(packed, 0, (size_t)n * sizeof(unsigned long long), stream);
    hipMemsetAsync(pooled, 0, 64 * 32 * sizeof(float), stream);

    // histogram (1 packed atomic/edge, ticket out) + dinv
    hist_kernel<<<(E + 255) / 256, NTHREADS, 0, stream>>>(dst, ew, packed, ticket, E);
    dinv_kernel<<<(n + 255) / 256, NTHREADS, 0, stream>>>(packed, dinv, n);

    // rowptr = exclusive_scan(cnt)
    scan1_kernel<<<nchunks, NTHREADS, 0, stream>>>(packed, rowptr, bsum, n);
    scan2_kernel<<<1, NTHREADS, 0, stream>>>(bsum, nchunks);
    scan3_kernel<<<(n + 255) / 256, NTHREADS, 0, stream>>>(rowptr, bsum, n, E);

    // atomic-free scatter of packed meta
    scatter_kernel<<<(E + 255) / 256, NTHREADS, 0, stream>>>(src, dst, ew, rowptr, ticket, meta, E);

    // layer 1
    gemm1_kernel<<<(n + 63) / 64, NTHREADS, 0, stream>>>(x, W1, dinv, g1, n);
    agg1_csr_kernel<<<(n + 3) / 4, NTHREADS, 0, stream>>>(rowptr, meta, g1, dinv, b1, y1, n);

    // layer 2
    gemm2_kernel<<<(n + 63) / 64, NTHREADS, 0, stream>>>(y1, W2, dinv, g2, n);
    agg2_csr_pool_kernel<<<(n + 3) / 4, NTHREADS, 0, stream>>>(
        rowptr, meta, g2, dinv, b2, batch, (unsigned int*)pooled, n);

    final_kernel<<<1, NTHREADS, 0, stream>>>(pooled, Wlin, blin, out);
}

// Round 7
// 586.147 us; speedup vs baseline: 2.8758x; 1.2379x over previous
//
#include <hip/hip_runtime.h>
#include <hip/hip_bf16.h>

// GCN: 2x GCNConv (sym-norm, self-loops) + ReLU, segment_max pool, linear.
// N=100000, E=3200000, G=64, IN=256, H1=64, H2=32. All fp32.
// CSR build with ZERO global atomics: two-level counting sort.
//   P1: per-block LDS histogram of dst>>9 -> cnt2d[bucket][block]
//   scan cnt2d (bucket-major) -> exact deterministic base for every (bucket,block)
//   P2: re-read chunk, LDS slot alloc from scanned bases, write (dst,meta) pairs
//   P3: per-bucket (512 nodes) LDS count+scan -> rowptr, dinv, final meta
// meta = (src<<15)|q15(ew). GEMMs write g = dinv*.(X@W);
// aggs compute relu(dinv_d*(sum ew*g[src] + g[d]) + b).

#define NTHREADS 256
#define SCAN_CHUNK 1024
#define NBP 512           // blocks in P1/P2
#define BSHIFT 9          // bucket = dst >> 9 (512 nodes/bucket)

// ---- P1: count edges per (bucket, block); no atomics to global ----
__global__ __launch_bounds__(NTHREADS) void p1_count_kernel(const int* __restrict__ dst,
                                                            unsigned int* __restrict__ cnt2d,
                                                            int nE, int nbuckets, int chunk) {
    __shared__ unsigned int hist[256];
    const int blk = blockIdx.x;
    const int t = threadIdx.x;
    hist[t] = 0;
    __syncthreads();
    const int e0 = blk * chunk;
    const int e1 = min(nE, e0 + chunk);
    for (int e = e0 + t; e < e1; e += NTHREADS)
        atomicAdd(&hist[dst[e] >> BSHIFT], 1u);
    __syncthreads();
    if (t < nbuckets) cnt2d[(size_t)t * NBP + blk] = hist[t];
}

// ---- exclusive scan (3 kernels, reused machinery) ----
__global__ __launch_bounds__(NTHREADS) void scan1_kernel(const unsigned int* __restrict__ in,
                                                         unsigned int* __restrict__ outv,
                                                         unsigned int* __restrict__ bsum, int n) {
    __shared__ unsigned int tmp[NTHREADS];
    const int base = blockIdx.x * SCAN_CHUNK;
    const int t = threadIdx.x;
    unsigned int v[4];
    #pragma unroll
    for (int k = 0; k < 4; ++k) {
        int i = base + t * 4 + k;
        v[k] = (i < n) ? in[i] : 0u;
    }
    unsigned int s = v[0] + v[1] + v[2] + v[3];
    tmp[t] = s;
    __syncthreads();
    for (int off = 1; off < NTHREADS; off <<= 1) {
        unsigned int val = (t >= off) ? tmp[t - off] : 0u;
        __syncthreads();
        tmp[t] += val;
        __syncthreads();
    }
    unsigned int excl = tmp[t] - s;
    if (t == NTHREADS - 1) bsum[blockIdx.x] = tmp[NTHREADS - 1];
    unsigned int run = excl;
    #pragma unroll
    for (int k = 0; k < 4; ++k) {
        int i = base + t * 4 + k;
        if (i < n) outv[i] = run;
        run += v[k];
    }
}

__global__ __launch_bounds__(NTHREADS) void scan2_kernel(unsigned int* __restrict__ bsum, int nb) {
    __shared__ unsigned int tmp[NTHREADS];
    int t = threadIdx.x;
    unsigned int v = (t < nb) ? bsum[t] : 0u;
    tmp[t] = v;
    __syncthreads();
    for (int off = 1; off < NTHREADS; off <<= 1) {
        unsigned int val = (t >= off) ? tmp[t - off] : 0u;
        __syncthreads();
        tmp[t] += val;
        __syncthreads();
    }
    if (t < nb) bsum[t] = tmp[t] - v;  // exclusive
}

__global__ __launch_bounds__(NTHREADS) void scan3_kernel(unsigned int* __restrict__ outv,
                                                         const unsigned int* __restrict__ bsum, int n) {
    int i = blockIdx.x * NTHREADS + threadIdx.x;
    if (i < n) outv[i] += bsum[i / SCAN_CHUNK];
}

// ---- P2: scatter (dst, meta) pairs into bucket regions; LDS slot alloc only ----
__global__ __launch_bounds__(NTHREADS) void p2_scatter_kernel(const int* __restrict__ src,
                                                              const int* __restrict__ dst,
                                                              const float* __restrict__ ew,
                                                              const unsigned int* __restrict__ base2d,
                                                              int2* __restrict__ pairs,
                                                              int nE, int nbuckets, int chunk) {
    __shared__ unsigned int fill[256];
    const int blk = blockIdx.x;
    const int t = threadIdx.x;
    if (t < nbuckets) fill[t] = base2d[(size_t)t * NBP + blk];
    __syncthreads();
    const int e0 = blk * chunk;
    const int e1 = min(nE, e0 + chunk);
    for (int e = e0 + t; e < e1; e += NTHREADS) {
        int d = dst[e];
        int s = src[e];
        unsigned int q = (unsigned int)(ew[e] * 32768.0f + 0.5f);
        q = q > 32767u ? 32767u : q;
        unsigned int m = ((unsigned int)s << 15) | q;
        unsigned int pos = atomicAdd(&fill[d >> BSHIFT], 1u);
        pairs[pos] = make_int2(d, (int)m);
    }
}

// ---- P3: per-bucket local CSR: rowptr, dinv, final meta ----
__global__ __launch_bounds__(1024) void p3_csr_kernel(const int2* __restrict__ pairs,
                                                      const unsigned int* __restrict__ base2d,
                                                      unsigned int* __restrict__ meta,
                                                      int* __restrict__ rowptr,
                                                      float* __restrict__ dinv,
                                                      int n, int nE, int nbuckets) {
    __shared__ unsigned int cnt[512];
    __shared__ unsigned int wsum[512];
    __shared__ unsigned int sc[512];
    __shared__ unsigned int fillL[512];
    const int b = blockIdx.x;
    const int t = threadIdx.x;
    const int node0 = b << BSHIFT;
    const int nloc = min(512, n - node0);
    const unsigned int e0 = base2d[(size_t)b * NBP];
    const unsigned int e1 = (b + 1 < nbuckets) ? base2d[(size_t)(b + 1) * NBP] : (unsigned int)nE;

    if (t < 512) { cnt[t] = 0u; wsum[t] = 0u; }
    __syncthreads();

    for (unsigned int e = e0 + t; e < e1; e += 1024) {
        int2 p = pairs[e];
        int dl = p.x & 511;
        atomicAdd(&cnt[dl], 1u);
        atomicAdd(&wsum[dl], (unsigned int)(p.y & 32767));
    }
    __syncthreads();

    if (t < 512) sc[t] = cnt[t];
    __syncthreads();
    for (int off = 1; off < 512; off <<= 1) {
        unsigned int v = (t >= off && t < 512) ? sc[t - off] : 0u;
        __syncthreads();
        if (t < 512) sc[t] += v;
        __syncthreads();
    }
    if (t < nloc) {
        unsigned int ex = sc[t] - cnt[t];   // exclusive scan
        rowptr[node0 + t] = (int)(e0 + ex);
        fillL[t] = ex;
        dinv[node0 + t] = rsqrtf(1.0f + (float)wsum[t] * (1.0f / 32768.0f));
    }
    if (b == nbuckets - 1 && t == 0) rowptr[n] = nE;
    __syncthreads();

    for (unsigned int e = e0 + t; e < e1; e += 1024) {
        int2 p = pairs[e];
        int dl = p.x & 511;
        unsigned int pos = e0 + atomicAdd(&fillL[dl], 1u);
        meta[pos] = (unsigned int)p.y;
    }
}

// ---- GEMM1: g1[n][64] = dinv[row] * (x[n][256] @ W1[256][64]) ----
__global__ __launch_bounds__(NTHREADS) void gemm1_kernel(const float* __restrict__ x,
                                                         const float* __restrict__ W,
                                                         const float* __restrict__ dinv,
                                                         float* __restrict__ g, int n) {
    __shared__ float xT[32][68];
    __shared__ float ws[32][64];
    const int t = threadIdx.x;
    const int row0 = blockIdx.x * 64;
    const int tc4 = (t & 15) * 4;
    const int tr4 = (t >> 4) * 4;
    float acc[4][4] = {};

    const int tx = t & 31;
    const int ty = t >> 5;

    for (int kb = 0; kb < 256; kb += 32) {
        #pragma unroll
        for (int rp = 0; rp < 8; ++rp) {
            int r = ty + rp * 8;
            int grow = row0 + r;
            float v = (grow < n) ? x[(size_t)grow * 256 + kb + tx] : 0.0f;
            xT[tx][r] = v;
        }
        #pragma unroll
        for (int p = 0; p < 8; ++p) {
            int idx = p * 256 + t;
            ws[idx >> 6][idx & 63] = W[(size_t)(kb + (idx >> 6)) * 64 + (idx & 63)];
        }
        __syncthreads();
        #pragma unroll
        for (int kk = 0; kk < 32; ++kk) {
            float4 xv = *(const float4*)&xT[kk][tr4];
            float4 wv = *(const float4*)&ws[kk][tc4];
            acc[0][0] += xv.x * wv.x; acc[0][1] += xv.x * wv.y; acc[0][2] += xv.x * wv.z; acc[0][3] += xv.x * wv.w;
            acc[1][0] += xv.y * wv.x; acc[1][1] += xv.y * wv.y; acc[1][2] += xv.y * wv.z; acc[1][3] += xv.y * wv.w;
            acc[2][0] += xv.z * wv.x; acc[2][1] += xv.z * wv.y; acc[2][2] += xv.z * wv.z; acc[2][3] += xv.z * wv.w;
            acc[3][0] += xv.w * wv.x; acc[3][1] += xv.w * wv.y; acc[3][2] += xv.w * wv.z; acc[3][3] += xv.w * wv.w;
        }
        __syncthreads();
    }
    #pragma unroll
    for (int r = 0; r < 4; ++r) {
        int grow = row0 + tr4 + r;
        if (grow < n) {
            float di = dinv[grow];
            float4 o = make_float4(di * acc[r][0], di * acc[r][1], di * acc[r][2], di * acc[r][3]);
            *(float4*)&g[(size_t)grow * 64 + tc4] = o;
        }
    }
}

// ---- agg1: wave-per-node, 16 lanes x float4, 4-way edge split ----
// y1 = relu(dinv_d * (sum ew*g1[src] + g1[d]) + b1)
__global__ __launch_bounds__(NTHREADS) void agg1_csr_kernel(const int* __restrict__ rowptr,
                                                            const unsigned int* __restrict__ meta,
                                                            const float* __restrict__ g1,
                                                            const float* __restrict__ dinv,
                                                            const float* __restrict__ b1,
                                                            float* __restrict__ y1, int n) {
    const int wid = (blockIdx.x * NTHREADS + threadIdx.x) >> 6;  // node
    if (wid >= n) return;
    const int l = threadIdx.x & 63;
    const int fg = l & 15, eg = l >> 4;
    const int j4 = fg * 4;
    const int beg = rowptr[wid], end = rowptr[wid + 1];
    const float di = dinv[wid];
    const float4 selfv = *(const float4*)&g1[(size_t)wid * 64 + j4];

    float4 acc = make_float4(0.f, 0.f, 0.f, 0.f);
    int k = beg + eg;
    for (; k + 4 < end; k += 8) {
        unsigned int m0 = meta[k];
        unsigned int m1 = meta[k + 4];
        float4 v0 = *(const float4*)&g1[(size_t)(m0 >> 15) * 64 + j4];
        float4 v1 = *(const float4*)&g1[(size_t)(m1 >> 15) * 64 + j4];
        float w0 = (float)(m0 & 32767u) * (1.0f / 32768.0f);
        float w1 = (float)(m1 & 32767u) * (1.0f / 32768.0f);
        acc.x = fmaf(w0, v0.x, acc.x); acc.y = fmaf(w0, v0.y, acc.y);
        acc.z = fmaf(w0, v0.z, acc.z); acc.w = fmaf(w0, v0.w, acc.w);
        acc.x = fmaf(w1, v1.x, acc.x); acc.y = fmaf(w1, v1.y, acc.y);
        acc.z = fmaf(w1, v1.z, acc.z); acc.w = fmaf(w1, v1.w, acc.w);
    }
    if (k < end) {
        unsigned int m = meta[k];
        float4 v = *(const float4*)&g1[(size_t)(m >> 15) * 64 + j4];
        float w = (float)(m & 32767u) * (1.0f / 32768.0f);
        acc.x = fmaf(w, v.x, acc.x); acc.y = fmaf(w, v.y, acc.y);
        acc.z = fmaf(w, v.z, acc.z); acc.w = fmaf(w, v.w, acc.w);
    }
    #pragma unroll
    for (int m = 16; m <= 32; m <<= 1) {
        acc.x += __shfl_xor(acc.x, m);
        acc.y += __shfl_xor(acc.y, m);
        acc.z += __shfl_xor(acc.z, m);
        acc.w += __shfl_xor(acc.w, m);
    }
    if (eg == 0) {
        float4 bb = *(const float4*)&b1[j4];
        float4 r;
        r.x = fmaxf(fmaf(di, acc.x + selfv.x, bb.x), 0.f);
        r.y = fmaxf(fmaf(di, acc.y + selfv.y, bb.y), 0.f);
        r.z = fmaxf(fmaf(di, acc.z + selfv.z, bb.z), 0.f);
        r.w = fmaxf(fmaf(di, acc.w + selfv.w, bb.w), 0.f);
        *(float4*)&y1[(size_t)wid * 64 + j4] = r;
    }
}

// ---- GEMM2: g2[n][32] = dinv[row] * (y1[n][64] @ W2[64][32]) ----
__global__ __launch_bounds__(NTHREADS) void gemm2_kernel(const float* __restrict__ y1,
                                                         const float* __restrict__ W,
                                                         const float* __restrict__ dinv,
                                                         float* __restrict__ g, int n) {
    __shared__ float xT[64][68];
    __shared__ float ws[64][32];
    const int t = threadIdx.x;
    const int row0 = blockIdx.x * 64;
    const int tc2 = (t & 15) * 2;
    const int tr4 = (t >> 4) * 4;
    float acc[4][2] = {};

    const int tx = t & 63;
    const int ty = t >> 6;
    #pragma unroll
    for (int rp = 0; rp < 16; ++rp) {
        int r = ty * 16 + rp;
        int grow = row0 + r;
        float v = (grow < n) ? y1[(size_t)grow * 64 + tx] : 0.0f;
        xT[tx][r] = v;
    }
    #pragma unroll
    for (int p = 0; p < 8; ++p) {
        int idx = p * 256 + t;
        ws[idx >> 5][idx & 31] = W[idx];
    }
    __syncthreads();
    #pragma unroll
    for (int kk = 0; kk < 64; ++kk) {
        float4 xv = *(const float4*)&xT[kk][tr4];
        float2 wv = *(const float2*)&ws[kk][tc2];
        acc[0][0] += xv.x * wv.x; acc[0][1] += xv.x * wv.y;
        acc[1][0] += xv.y * wv.x; acc[1][1] += xv.y * wv.y;
        acc[2][0] += xv.z * wv.x; acc[2][1] += xv.z * wv.y;
        acc[3][0] += xv.w * wv.x; acc[3][1] += xv.w * wv.y;
    }
    #pragma unroll
    for (int r = 0; r < 4; ++r) {
        int grow = row0 + tr4 + r;
        if (grow < n) {
            float di = dinv[grow];
            float2 o = make_float2(di * acc[r][0], di * acc[r][1]);
            *(float2*)&g[(size_t)grow * 32 + tc2] = o;
        }
    }
}

// ---- agg2: wave-per-node, 8 lanes x float4, 8-way edge split, LDS pool ----
__global__ __launch_bounds__(NTHREADS) void agg2_csr_pool_kernel(const int* __restrict__ rowptr,
                                                                 const unsigned int* __restrict__ meta,
                                                                 const float* __restrict__ g2,
                                                                 const float* __restrict__ dinv,
                                                                 const float* __restrict__ b2,
                                                                 const int* __restrict__ batch,
                                                                 unsigned int* __restrict__ pooled,
                                                                 int n) {
    __shared__ float smax[4][32];
    __shared__ int sb[4];
    const int w = threadIdx.x >> 6;            // wave in block
    const int l = threadIdx.x & 63;
    const int node = blockIdx.x * 4 + w;
    const bool active = node < n;
    const int fg = l & 7, eg = l >> 3;
    const int j4 = fg * 4;

    if (l == 0) sb[w] = active ? batch[node] : -1;

    if (active) {
        const int beg = rowptr[node], end = rowptr[node + 1];
        const float di = dinv[node];
        const float4 selfv = *(const float4*)&g2[(size_t)node * 32 + j4];

        float4 acc = make_float4(0.f, 0.f, 0.f, 0.f);
        int k = beg + eg;
        for (; k + 8 < end; k += 16) {
            unsigned int m0 = meta[k];
            unsigned int m1 = meta[k + 8];
            float4 v0 = *(const float4*)&g2[(size_t)(m0 >> 15) * 32 + j4];
            float4 v1 = *(const float4*)&g2[(size_t)(m1 >> 15) * 32 + j4];
            float w0 = (float)(m0 & 32767u) * (1.0f / 32768.0f);
            float w1 = (float)(m1 & 32767u) * (1.0f / 32768.0f);
            acc.x = fmaf(w0, v0.x, acc.x); acc.y = fmaf(w0, v0.y, acc.y);
            acc.z = fmaf(w0, v0.z, acc.z); acc.w = fmaf(w0, v0.w, acc.w);
            acc.x = fmaf(w1, v1.x, acc.x); acc.y = fmaf(w1, v1.y, acc.y);
            acc.z = fmaf(w1, v1.z, acc.z); acc.w = fmaf(w1, v1.w, acc.w);
        }
        if (k < end) {
            unsigned int m = meta[k];
            float4 v = *(const float4*)&g2[(size_t)(m >> 15) * 32 + j4];
            float wq = (float)(m & 32767u) * (1.0f / 32768.0f);
            acc.x = fmaf(wq, v.x, acc.x); acc.y = fmaf(wq, v.y, acc.y);
            acc.z = fmaf(wq, v.z, acc.z); acc.w = fmaf(wq, v.w, acc.w);
        }
        #pragma unroll
        for (int m = 8; m <= 32; m <<= 1) {
            acc.x += __shfl_xor(acc.x, m);
            acc.y += __shfl_xor(acc.y, m);
            acc.z += __shfl_xor(acc.z, m);
            acc.w += __shfl_xor(acc.w, m);
        }
        if (eg == 0) {
            float4 bb = *(const float4*)&b2[j4];
            float4 r;
            r.x = fmaxf(fmaf(di, acc.x + selfv.x, bb.x), 0.f);
            r.y = fmaxf(fmaf(di, acc.y + selfv.y, bb.y), 0.f);
            r.z = fmaxf(fmaf(di, acc.z + selfv.z, bb.z), 0.f);
            r.w = fmaxf(fmaf(di, acc.w + selfv.w, bb.w), 0.f);
            *(float4*)&smax[w][j4] = r;
        }
    }
    __syncthreads();
    const int t = threadIdx.x;
    if (t < 32) {
        int b0 = sb[0], b1_ = sb[1], b2_ = sb[2], b3_ = sb[3];
        if (b0 >= 0 && b0 == b1_ && b0 == b2_ && b0 == b3_) {
            float v = fmaxf(fmaxf(smax[0][t], smax[1][t]), fmaxf(smax[2][t], smax[3][t]));
            atomicMax(&pooled[b0 * 32 + t], __float_as_uint(v));
        } else {
            #pragma unroll
            for (int ww = 0; ww < 4; ++ww) {
                if (sb[ww] >= 0)
                    atomicMax(&pooled[sb[ww] * 32 + t], __float_as_uint(smax[ww][t]));
            }
        }
    }
}

// ---------------- final: out[64][4] = pooled[64][32] @ Wlin[32][4] + blin ----------------
__global__ __launch_bounds__(NTHREADS) void final_kernel(const float* __restrict__ pooled,
                                                         const float* __restrict__ Wlin,
                                                         const float* __restrict__ blin,
                                                         float* __restrict__ out) {
    int t = threadIdx.x;  // 256 = 64 graphs * 4 cols
    int g = t >> 2, c = t & 3;
    float s = blin[c];
    #pragma unroll
    for (int j = 0; j < 32; ++j) s += pooled[g * 32 + j] * Wlin[j * 4 + c];
    out[g * 4 + c] = s;
}

extern "C" void kernel_launch(void* const* d_in, const int* in_sizes, int n_in,
                              void* d_out, int out_size, void* d_ws, size_t ws_size,
                              hipStream_t stream) {
    const float* x     = (const float*)d_in[0];
    const int*   ei    = (const int*)d_in[1];
    const float* ew    = (const float*)d_in[2];
    const int*   batch = (const int*)d_in[3];
    const float* W1    = (const float*)d_in[4];
    const float* b1    = (const float*)d_in[5];
    const float* W2    = (const float*)d_in[6];
    const float* b2    = (const float*)d_in[7];
    const float* Wlin  = (const float*)d_in[8];
    const float* blin  = (const float*)d_in[9];
    float* out = (float*)d_out;

    const int E = in_sizes[2];   // 3200000
    const int n = in_sizes[3];   // 100000
    const int* src = ei;
    const int* dst = ei + E;

    const int nbuckets = (n + 511) >> BSHIFT;            // 196
    const int chunk = (E + NBP - 1) / NBP;               // 6250
    const int scanlen = nbuckets * NBP;                  // 100352
    const int nchunks = (scanlen + SCAN_CHUNK - 1) / SCAN_CHUNK;  // 98

    // workspace layout (4-byte units)
    auto al = [](size_t v) { return (v + 63) & ~(size_t)63; };
    float* ws = (float*)d_ws;
    size_t off = 0;
    unsigned int* cnt2d  = (unsigned int*)(ws + off); off += al(scanlen);
    unsigned int* base2d = (unsigned int*)(ws + off); off += al(scanlen);
    unsigned int* bsum   = (unsigned int*)(ws + off); off += al(256);
    float* dinv    = ws + off; off += al(n);
    int*   rowptr  = (int*)(ws + off); off += al(n + 1);
    unsigned int* meta = (unsigned int*)(ws + off); off += al(E);
    float* g1      = ws + off; off += al((size_t)n * 64);   // reused as g2
    float* y1      = ws + off; off += al((size_t)n * 64);   // ALSO aliases pairs (dead after P3)
    float* pooled  = ws + off; off += al(64 * 32);
    float* g2 = g1;             // g1 dead after agg1; gemm2 overwrites with g2
    int2*  pairs = (int2*)y1;   // E*8 bytes == n*64*4 bytes; pairs dead before agg1 writes y1

    hipMemsetAsync(pooled, 0, 64 * 32 * sizeof(float), stream);

    // CSR build (no global atomics)
    p1_count_kernel<<<NBP, NTHREADS, 0, stream>>>(dst, cnt2d, E, nbuckets, chunk);
    scan1_kernel<<<nchunks, NTHREADS, 0, stream>>>(cnt2d, base2d, bsum, scanlen);
    scan2_kernel<<<1, NTHREADS, 0, stream>>>(bsum, nchunks);
    scan3_kernel<<<(scanlen + 255) / 256, NTHREADS, 0, stream>>>(base2d, bsum, scanlen);
    p2_scatter_kernel<<<NBP, NTHREADS, 0, stream>>>(src, dst, ew, base2d, pairs, E, nbuckets, chunk);
    p3_csr_kernel<<<nbuckets, 1024, 0, stream>>>(pairs, base2d, meta, rowptr, dinv, n, E, nbuckets);

    // layer 1
    gemm1_kernel<<<(n + 63) / 64, NTHREADS, 0, stream>>>(x, W1, dinv, g1, n);
    agg1_csr_kernel<<<(n + 3) / 4, NTHREADS, 0, stream>>>(rowptr, meta, g1, dinv, b1, y1, n);

    // layer 2
    gemm2_kernel<<<(n + 63) / 64, NTHREADS, 0, stream>>>(y1, W2, dinv, g2, n);
    agg2_csr_pool_kernel<<<(n + 3) / 4, NTHREADS, 0, stream>>>(
        rowptr, meta, g2, dinv, b2, batch, (unsigned int*)pooled, n);

    final_kernel<<<1, NTHREADS, 0, stream>>>(pooled, Wlin, blin, out);
}

// Round 8
// 542.662 us; speedup vs baseline: 3.1063x; 1.0801x over previous
//
#include <hip/hip_runtime.h>
#include <hip/hip_bf16.h>

// GCN: 2x GCNConv (sym-norm, self-loops) + ReLU, segment_max pool, linear.
// N=100000, E=3200000, G=64, IN=256, H1=64, H2=32. All fp32.
// CSR build with ZERO global atomics: two-level counting sort (P1/scan/P2/P3).
// meta = (src<<15)|q15(ew). GEMMs write g = dinv*.(X@W);
// aggs compute relu(dinv_d*(sum ew*g[src] + g[d]) + b).
// gemm1: 128x64 tile, 8x4 acc/thread, K-chunk 32 (3 LDS b128 reads : 32 FMA).

#define NTHREADS 256
#define SCAN_CHUNK 1024
#define NBP 512           // blocks in P1/P2
#define BSHIFT 9          // bucket = dst >> 9 (512 nodes/bucket)

// ---- P1: count edges per (bucket, block); no atomics to global ----
__global__ __launch_bounds__(NTHREADS) void p1_count_kernel(const int* __restrict__ dst,
                                                            unsigned int* __restrict__ cnt2d,
                                                            int nE, int nbuckets, int chunk) {
    __shared__ unsigned int hist[256];
    const int blk = blockIdx.x;
    const int t = threadIdx.x;
    hist[t] = 0;
    __syncthreads();
    const int e0 = blk * chunk;
    const int e1 = min(nE, e0 + chunk);
    for (int e = e0 + t; e < e1; e += NTHREADS)
        atomicAdd(&hist[dst[e] >> BSHIFT], 1u);
    __syncthreads();
    if (t < nbuckets) cnt2d[(size_t)t * NBP + blk] = hist[t];
}

// ---- exclusive scan (3 kernels) ----
__global__ __launch_bounds__(NTHREADS) void scan1_kernel(const unsigned int* __restrict__ in,
                                                         unsigned int* __restrict__ outv,
                                                         unsigned int* __restrict__ bsum, int n) {
    __shared__ unsigned int tmp[NTHREADS];
    const int base = blockIdx.x * SCAN_CHUNK;
    const int t = threadIdx.x;
    unsigned int v[4];
    #pragma unroll
    for (int k = 0; k < 4; ++k) {
        int i = base + t * 4 + k;
        v[k] = (i < n) ? in[i] : 0u;
    }
    unsigned int s = v[0] + v[1] + v[2] + v[3];
    tmp[t] = s;
    __syncthreads();
    for (int off = 1; off < NTHREADS; off <<= 1) {
        unsigned int val = (t >= off) ? tmp[t - off] : 0u;
        __syncthreads();
        tmp[t] += val;
        __syncthreads();
    }
    unsigned int excl = tmp[t] - s;
    if (t == NTHREADS - 1) bsum[blockIdx.x] = tmp[NTHREADS - 1];
    unsigned int run = excl;
    #pragma unroll
    for (int k = 0; k < 4; ++k) {
        int i = base + t * 4 + k;
        if (i < n) outv[i] = run;
        run += v[k];
    }
}

__global__ __launch_bounds__(NTHREADS) void scan2_kernel(unsigned int* __restrict__ bsum, int nb) {
    __shared__ unsigned int tmp[NTHREADS];
    int t = threadIdx.x;
    unsigned int v = (t < nb) ? bsum[t] : 0u;
    tmp[t] = v;
    __syncthreads();
    for (int off = 1; off < NTHREADS; off <<= 1) {
        unsigned int val = (t >= off) ? tmp[t - off] : 0u;
        __syncthreads();
        tmp[t] += val;
        __syncthreads();
    }
    if (t < nb) bsum[t] = tmp[t] - v;  // exclusive
}

__global__ __launch_bounds__(NTHREADS) void scan3_kernel(unsigned int* __restrict__ outv,
                                                         const unsigned int* __restrict__ bsum, int n) {
    int i = blockIdx.x * NTHREADS + threadIdx.x;
    if (i < n) outv[i] += bsum[i / SCAN_CHUNK];
}

// ---- P2: scatter (dst, meta) pairs into bucket regions; LDS slot alloc only ----
__global__ __launch_bounds__(NTHREADS) void p2_scatter_kernel(const int* __restrict__ src,
                                                              const int* __restrict__ dst,
                                                              const float* __restrict__ ew,
                                                              const unsigned int* __restrict__ base2d,
                                                              int2* __restrict__ pairs,
                                                              int nE, int nbuckets, int chunk) {
    __shared__ unsigned int fill[256];
    const int blk = blockIdx.x;
    const int t = threadIdx.x;
    if (t < nbuckets) fill[t] = base2d[(size_t)t * NBP + blk];
    __syncthreads();
    const int e0 = blk * chunk;
    const int e1 = min(nE, e0 + chunk);
    for (int e = e0 + t; e < e1; e += NTHREADS) {
        int d = dst[e];
        int s = src[e];
        unsigned int q = (unsigned int)(ew[e] * 32768.0f + 0.5f);
        q = q > 32767u ? 32767u : q;
        unsigned int m = ((unsigned int)s << 15) | q;
        unsigned int pos = atomicAdd(&fill[d >> BSHIFT], 1u);
        pairs[pos] = make_int2(d, (int)m);
    }
}

// ---- P3: per-bucket local CSR: rowptr, dinv, final meta ----
__global__ __launch_bounds__(1024) void p3_csr_kernel(const int2* __restrict__ pairs,
                                                      const unsigned int* __restrict__ base2d,
                                                      unsigned int* __restrict__ meta,
                                                      int* __restrict__ rowptr,
                                                      float* __restrict__ dinv,
                                                      int n, int nE, int nbuckets) {
    __shared__ unsigned int cnt[512];
    __shared__ unsigned int wsum[512];
    __shared__ unsigned int sc[512];
    __shared__ unsigned int fillL[512];
    const int b = blockIdx.x;
    const int t = threadIdx.x;
    const int node0 = b << BSHIFT;
    const int nloc = min(512, n - node0);
    const unsigned int e0 = base2d[(size_t)b * NBP];
    const unsigned int e1 = (b + 1 < nbuckets) ? base2d[(size_t)(b + 1) * NBP] : (unsigned int)nE;

    if (t < 512) { cnt[t] = 0u; wsum[t] = 0u; }
    __syncthreads();

    for (unsigned int e = e0 + t; e < e1; e += 1024) {
        int2 p = pairs[e];
        int dl = p.x & 511;
        atomicAdd(&cnt[dl], 1u);
        atomicAdd(&wsum[dl], (unsigned int)(p.y & 32767));
    }
    __syncthreads();

    if (t < 512) sc[t] = cnt[t];
    __syncthreads();
    for (int off = 1; off < 512; off <<= 1) {
        unsigned int v = (t >= off && t < 512) ? sc[t - off] : 0u;
        __syncthreads();
        if (t < 512) sc[t] += v;
        __syncthreads();
    }
    if (t < nloc) {
        unsigned int ex = sc[t] - cnt[t];   // exclusive scan
        rowptr[node0 + t] = (int)(e0 + ex);
        fillL[t] = ex;
        dinv[node0 + t] = rsqrtf(1.0f + (float)wsum[t] * (1.0f / 32768.0f));
    }
    if (b == nbuckets - 1 && t == 0) rowptr[n] = nE;
    __syncthreads();

    for (unsigned int e = e0 + t; e < e1; e += 1024) {
        int2 p = pairs[e];
        int dl = p.x & 511;
        unsigned int pos = e0 + atomicAdd(&fillL[dl], 1u);
        meta[pos] = (unsigned int)p.y;
    }
}

// ---- GEMM1: g1[n][64] = dinv[row] * (x[n][256] @ W1[256][64]) ----
// 128x64 tile, 256 threads, 8x4 outputs/thread, K-chunk 32.
__global__ __launch_bounds__(NTHREADS) void gemm1_kernel(const float* __restrict__ x,
                                                         const float* __restrict__ W,
                                                         const float* __restrict__ dinv,
                                                         float* __restrict__ g, int n) {
    __shared__ float xT[32][132];   // [k][row], pad 132 for conflict-free
    __shared__ float ws[32][64];    // [k][col]
    const int t = threadIdx.x;
    const int row0 = blockIdx.x * 128;
    const int tc4 = (t & 15) * 4;   // output cols
    const int tr8 = (t >> 4) * 8;   // output rows
    const int kq = (t & 7) * 4;     // staging: k-quad within chunk
    const int rsub = t >> 3;        // staging: row within 32-row pass
    float acc[8][4] = {};

    for (int kb = 0; kb < 256; kb += 32) {
        // stage x transposed: 4 passes x 32 rows, coalesced float4 along k
        #pragma unroll
        for (int p = 0; p < 4; ++p) {
            int r = p * 32 + rsub;
            int grow = row0 + r;
            float4 v = make_float4(0.f, 0.f, 0.f, 0.f);
            if (grow < n) v = *(const float4*)&x[(size_t)grow * 256 + kb + kq];
            xT[kq + 0][r] = v.x; xT[kq + 1][r] = v.y;
            xT[kq + 2][r] = v.z; xT[kq + 3][r] = v.w;
        }
        // stage W: 2 passes, b128
        #pragma unroll
        for (int p = 0; p < 2; ++p) {
            int k = p * 16 + (t >> 4);
            *(float4*)&ws[k][tc4] = *(const float4*)&W[(size_t)(kb + k) * 64 + tc4];
        }
        __syncthreads();
        #pragma unroll
        for (int kk = 0; kk < 32; ++kk) {
            float4 wv = *(const float4*)&ws[kk][tc4];
            float4 xa = *(const float4*)&xT[kk][tr8];
            float4 xb = *(const float4*)&xT[kk][tr8 + 4];
            float xr[8] = {xa.x, xa.y, xa.z, xa.w, xb.x, xb.y, xb.z, xb.w};
            #pragma unroll
            for (int r = 0; r < 8; ++r) {
                acc[r][0] = fmaf(xr[r], wv.x, acc[r][0]);
                acc[r][1] = fmaf(xr[r], wv.y, acc[r][1]);
                acc[r][2] = fmaf(xr[r], wv.z, acc[r][2]);
                acc[r][3] = fmaf(xr[r], wv.w, acc[r][3]);
            }
        }
        __syncthreads();
    }
    #pragma unroll
    for (int r = 0; r < 8; ++r) {
        int grow = row0 + tr8 + r;
        if (grow < n) {
            float di = dinv[grow];
            float4 o = make_float4(di * acc[r][0], di * acc[r][1],
                                   di * acc[r][2], di * acc[r][3]);
            *(float4*)&g[(size_t)grow * 64 + tc4] = o;
        }
    }
}

// ---- agg1: wave-per-node, 16 lanes x float4, 4-way edge split ----
// y1 = relu(dinv_d * (sum ew*g1[src] + g1[d]) + b1)
__global__ __launch_bounds__(NTHREADS) void agg1_csr_kernel(const int* __restrict__ rowptr,
                                                            const unsigned int* __restrict__ meta,
                                                            const float* __restrict__ g1,
                                                            const float* __restrict__ dinv,
                                                            const float* __restrict__ b1,
                                                            float* __restrict__ y1, int n) {
    const int wid = (blockIdx.x * NTHREADS + threadIdx.x) >> 6;  // node
    if (wid >= n) return;
    const int l = threadIdx.x & 63;
    const int fg = l & 15, eg = l >> 4;
    const int j4 = fg * 4;
    const int beg = rowptr[wid], end = rowptr[wid + 1];
    const float di = dinv[wid];
    const float4 selfv = *(const float4*)&g1[(size_t)wid * 64 + j4];

    float4 acc = make_float4(0.f, 0.f, 0.f, 0.f);
    int k = beg + eg;
    for (; k + 4 < end; k += 8) {
        unsigned int m0 = meta[k];
        unsigned int m1 = meta[k + 4];
        float4 v0 = *(const float4*)&g1[(size_t)(m0 >> 15) * 64 + j4];
        float4 v1 = *(const float4*)&g1[(size_t)(m1 >> 15) * 64 + j4];
        float w0 = (float)(m0 & 32767u) * (1.0f / 32768.0f);
        float w1 = (float)(m1 & 32767u) * (1.0f / 32768.0f);
        acc.x = fmaf(w0, v0.x, acc.x); acc.y = fmaf(w0, v0.y, acc.y);
        acc.z = fmaf(w0, v0.z, acc.z); acc.w = fmaf(w0, v0.w, acc.w);
        acc.x = fmaf(w1, v1.x, acc.x); acc.y = fmaf(w1, v1.y, acc.y);
        acc.z = fmaf(w1, v1.z, acc.z); acc.w = fmaf(w1, v1.w, acc.w);
    }
    if (k < end) {
        unsigned int m = meta[k];
        float4 v = *(const float4*)&g1[(size_t)(m >> 15) * 64 + j4];
        float w = (float)(m & 32767u) * (1.0f / 32768.0f);
        acc.x = fmaf(w, v.x, acc.x); acc.y = fmaf(w, v.y, acc.y);
        acc.z = fmaf(w, v.z, acc.z); acc.w = fmaf(w, v.w, acc.w);
    }
    #pragma unroll
    for (int m = 16; m <= 32; m <<= 1) {
        acc.x += __shfl_xor(acc.x, m);
        acc.y += __shfl_xor(acc.y, m);
        acc.z += __shfl_xor(acc.z, m);
        acc.w += __shfl_xor(acc.w, m);
    }
    if (eg == 0) {
        float4 bb = *(const float4*)&b1[j4];
        float4 r;
        r.x = fmaxf(fmaf(di, acc.x + selfv.x, bb.x), 0.f);
        r.y = fmaxf(fmaf(di, acc.y + selfv.y, bb.y), 0.f);
        r.z = fmaxf(fmaf(di, acc.z + selfv.z, bb.z), 0.f);
        r.w = fmaxf(fmaf(di, acc.w + selfv.w, bb.w), 0.f);
        *(float4*)&y1[(size_t)wid * 64 + j4] = r;
    }
}

// ---- GEMM2: g2[n][32] = dinv[row] * (y1[n][64] @ W2[64][32]) ----
__global__ __launch_bounds__(NTHREADS) void gemm2_kernel(const float* __restrict__ y1,
                                                         const float* __restrict__ W,
                                                         const float* __restrict__ dinv,
                                                         float* __restrict__ g, int n) {
    __shared__ float xT[64][68];
    __shared__ float ws[64][32];
    const int t = threadIdx.x;
    const int row0 = blockIdx.x * 64;
    const int tc2 = (t & 15) * 2;
    const int tr4 = (t >> 4) * 4;
    float acc[4][2] = {};

    const int tx = t & 63;
    const int ty = t >> 6;
    #pragma unroll
    for (int rp = 0; rp < 16; ++rp) {
        int r = ty * 16 + rp;
        int grow = row0 + r;
        float v = (grow < n) ? y1[(size_t)grow * 64 + tx] : 0.0f;
        xT[tx][r] = v;
    }
    #pragma unroll
    for (int p = 0; p < 8; ++p) {
        int idx = p * 256 + t;
        ws[idx >> 5][idx & 31] = W[idx];
    }
    __syncthreads();
    #pragma unroll
    for (int kk = 0; kk < 64; ++kk) {
        float4 xv = *(const float4*)&xT[kk][tr4];
        float2 wv = *(const float2*)&ws[kk][tc2];
        acc[0][0] += xv.x * wv.x; acc[0][1] += xv.x * wv.y;
        acc[1][0] += xv.y * wv.x; acc[1][1] += xv.y * wv.y;
        acc[2][0] += xv.z * wv.x; acc[2][1] += xv.z * wv.y;
        acc[3][0] += xv.w * wv.x; acc[3][1] += xv.w * wv.y;
    }
    #pragma unroll
    for (int r = 0; r < 4; ++r) {
        int grow = row0 + tr4 + r;
        if (grow < n) {
            float di = dinv[grow];
            float2 o = make_float2(di * acc[r][0], di * acc[r][1]);
            *(float2*)&g[(size_t)grow * 32 + tc2] = o;
        }
    }
}

// ---- agg2: wave-per-node, 8 lanes x float4, 8-way edge split, LDS pool ----
__global__ __launch_bounds__(NTHREADS) void agg2_csr_pool_kernel(const int* __restrict__ rowptr,
                                                                 const unsigned int* __restrict__ meta,
                                                                 const float* __restrict__ g2,
                                                                 const float* __restrict__ dinv,
                                                                 const float* __restrict__ b2,
                                                                 const int* __restrict__ batch,
                                                                 unsigned int* __restrict__ pooled,
                                                                 int n) {
    __shared__ float smax[4][32];
    __shared__ int sb[4];
    const int w = threadIdx.x >> 6;            // wave in block
    const int l = threadIdx.x & 63;
    const int node = blockIdx.x * 4 + w;
    const bool active = node < n;
    const int fg = l & 7, eg = l >> 3;
    const int j4 = fg * 4;

    if (l == 0) sb[w] = active ? batch[node] : -1;

    if (active) {
        const int beg = rowptr[node], end = rowptr[node + 1];
        const float di = dinv[node];
        const float4 selfv = *(const float4*)&g2[(size_t)node * 32 + j4];

        float4 acc = make_float4(0.f, 0.f, 0.f, 0.f);
        int k = beg + eg;
        for (; k + 8 < end; k += 16) {
            unsigned int m0 = meta[k];
            unsigned int m1 = meta[k + 8];
            float4 v0 = *(const float4*)&g2[(size_t)(m0 >> 15) * 32 + j4];
            float4 v1 = *(const float4*)&g2[(size_t)(m1 >> 15) * 32 + j4];
            float w0 = (float)(m0 & 32767u) * (1.0f / 32768.0f);
            float w1 = (float)(m1 & 32767u) * (1.0f / 32768.0f);
            acc.x = fmaf(w0, v0.x, acc.x); acc.y = fmaf(w0, v0.y, acc.y);
            acc.z = fmaf(w0, v0.z, acc.z); acc.w = fmaf(w0, v0.w, acc.w);
            acc.x = fmaf(w1, v1.x, acc.x); acc.y = fmaf(w1, v1.y, acc.y);
            acc.z = fmaf(w1, v1.z, acc.z); acc.w = fmaf(w1, v1.w, acc.w);
        }
        if (k < end) {
            unsigned int m = meta[k];
            float4 v = *(const float4*)&g2[(size_t)(m >> 15) * 32 + j4];
            float wq = (float)(m & 32767u) * (1.0f / 32768.0f);
            acc.x = fmaf(wq, v.x, acc.x); acc.y = fmaf(wq, v.y, acc.y);
            acc.z = fmaf(wq, v.z, acc.z); acc.w = fmaf(wq, v.w, acc.w);
        }
        #pragma unroll
        for (int m = 8; m <= 32; m <<= 1) {
            acc.x += __shfl_xor(acc.x, m);
            acc.y += __shfl_xor(acc.y, m);
            acc.z += __shfl_xor(acc.z, m);
            acc.w += __shfl_xor(acc.w, m);
        }
        if (eg == 0) {
            float4 bb = *(const float4*)&b2[j4];
            float4 r;
            r.x = fmaxf(fmaf(di, acc.x + selfv.x, bb.x), 0.f);
            r.y = fmaxf(fmaf(di, acc.y + selfv.y, bb.y), 0.f);
            r.z = fmaxf(fmaf(di, acc.z + selfv.z, bb.z), 0.f);
            r.w = fmaxf(fmaf(di, acc.w + selfv.w, bb.w), 0.f);
            *(float4*)&smax[w][j4] = r;
        }
    }
    __syncthreads();
    const int t = threadIdx.x;
    if (t < 32) {
        int b0 = sb[0], b1_ = sb[1], b2_ = sb[2], b3_ = sb[3];
        if (b0 >= 0 && b0 == b1_ && b0 == b2_ && b0 == b3_) {
            float v = fmaxf(fmaxf(smax[0][t], smax[1][t]), fmaxf(smax[2][t], smax[3][t]));
            atomicMax(&pooled[b0 * 32 + t], __float_as_uint(v));
        } else {
            #pragma unroll
            for (int ww = 0; ww < 4; ++ww) {
                if (sb[ww] >= 0)
                    atomicMax(&pooled[sb[ww] * 32 + t], __float_as_uint(smax[ww][t]));
            }
        }
    }
}

// ---------------- final: out[64][4] = pooled[64][32] @ Wlin[32][4] + blin ----------------
__global__ __launch_bounds__(NTHREADS) void final_kernel(const float* __restrict__ pooled,
                                                         const float* __restrict__ Wlin,
                                                         const float* __restrict__ blin,
                                                         float* __restrict__ out) {
    int t = threadIdx.x;  // 256 = 64 graphs * 4 cols
    int g = t >> 2, c = t & 3;
    float s = blin[c];
    #pragma unroll
    for (int j = 0; j < 32; ++j) s += pooled[g * 32 + j] * Wlin[j * 4 + c];
    out[g * 4 + c] = s;
}

extern "C" void kernel_launch(void* const* d_in, const int* in_sizes, int n_in,
                              void* d_out, int out_size, void* d_ws, size_t ws_size,
                              hipStream_t stream) {
    const float* x     = (const float*)d_in[0];
    const int*   ei    = (const int*)d_in[1];
    const float* ew    = (const float*)d_in[2];
    const int*   batch = (const int*)d_in[3];
    const float* W1    = (const float*)d_in[4];
    const float* b1    = (const float*)d_in[5];
    const float* W2    = (const float*)d_in[6];
    const float* b2    = (const float*)d_in[7];
    const float* Wlin  = (const float*)d_in[8];
    const float* blin  = (const float*)d_in[9];
    float* out = (float*)d_out;

    const int E = in_sizes[2];   // 3200000
    const int n = in_sizes[3];   // 100000
    const int* src = ei;
    const int* dst = ei + E;

    const int nbuckets = (n + 511) >> BSHIFT;            // 196
    const int chunk = (E + NBP - 1) / NBP;               // 6250
    const int scanlen = nbuckets * NBP;                  // 100352
    const int nchunks = (scanlen + SCAN_CHUNK - 1) / SCAN_CHUNK;  // 98

    // workspace layout (4-byte units)
    auto al = [](size_t v) { return (v + 63) & ~(size_t)63; };
    float* ws = (float*)d_ws;
    size_t off = 0;
    unsigned int* cnt2d  = (unsigned int*)(ws + off); off += al(scanlen);
    unsigned int* base2d = (unsigned int*)(ws + off); off += al(scanlen);
    unsigned int* bsum   = (unsigned int*)(ws + off); off += al(256);
    float* dinv    = ws + off; off += al(n);
    int*   rowptr  = (int*)(ws + off); off += al(n + 1);
    unsigned int* meta = (unsigned int*)(ws + off); off += al(E);
    float* g1      = ws + off; off += al((size_t)n * 64);   // reused as g2
    float* y1      = ws + off; off += al((size_t)n * 64);   // ALSO aliases pairs (dead after P3)
    float* pooled  = ws + off; off += al(64 * 32);
    float* g2 = g1;             // g1 dead after agg1; gemm2 overwrites with g2
    int2*  pairs = (int2*)y1;   // E*8 bytes == n*64*4 bytes; pairs dead before agg1 writes y1

    hipMemsetAsync(pooled, 0, 64 * 32 * sizeof(float), stream);

    // CSR build (no global atomics)
    p1_count_kernel<<<NBP, NTHREADS, 0, stream>>>(dst, cnt2d, E, nbuckets, chunk);
    scan1_kernel<<<nchunks, NTHREADS, 0, stream>>>(cnt2d, base2d, bsum, scanlen);
    scan2_kernel<<<1, NTHREADS, 0, stream>>>(bsum, nchunks);
    scan3_kernel<<<(scanlen + 255) / 256, NTHREADS, 0, stream>>>(base2d, bsum, scanlen);
    p2_scatter_kernel<<<NBP, NTHREADS, 0, stream>>>(src, dst, ew, base2d, pairs, E, nbuckets, chunk);
    p3_csr_kernel<<<nbuckets, 1024, 0, stream>>>(pairs, base2d, meta, rowptr, dinv, n, E, nbuckets);

    // layer 1
    gemm1_kernel<<<(n + 127) / 128, NTHREADS, 0, stream>>>(x, W1, dinv, g1, n);
    agg1_csr_kernel<<<(n + 3) / 4, NTHREADS, 0, stream>>>(rowptr, meta, g1, dinv, b1, y1, n);

    // layer 2
    gemm2_kernel<<<(n + 63) / 64, NTHREADS, 0, stream>>>(y1, W2, dinv, g2, n);
    agg2_csr_pool_kernel<<<(n + 3) / 4, NTHREADS, 0, stream>>>(
        rowptr, meta, g2, dinv, b2, batch, (unsigned int*)pooled, n);

    final_kernel<<<1, NTHREADS, 0, stream>>>(pooled, Wlin, blin, out);
}

// Round 9
// 503.212 us; speedup vs baseline: 3.3498x; 1.0784x over previous
//
#include <hip/hip_runtime.h>
#include <hip/hip_bf16.h>

// GCN: 2x GCNConv (sym-norm, self-loops) + ReLU, segment_max pool, linear.
// N=100000, E=3200000, G=64, IN=256, H1=64, H2=32.
// CSR build with ZERO global atomics (counting sort P1/scan/P2/P3).
// meta = (src<<15)|q15(ew). GEMMs write g = bf16(dinv*.(X@W)) -- halves the
// random-gather bytes in the agg kernels (they were L2-miss-traffic-bound at
// 3.7 TB/s). aggs compute relu(dinv_d*(sum ew*g[src] + g[d]) + b) in fp32.

#define NTHREADS 256
#define SCAN_CHUNK 1024
#define NBP 512           // blocks in P1/P2
#define BSHIFT 9          // bucket = dst >> 9 (512 nodes/bucket)

__device__ __forceinline__ unsigned short f2bf(float f) {
    unsigned int u = __float_as_uint(f);
    u = (u + 0x7FFFu + ((u >> 16) & 1u)) >> 16;   // round-to-nearest-even
    return (unsigned short)u;
}
__device__ __forceinline__ float bf2f(unsigned short s) {
    return __uint_as_float((unsigned int)s << 16);
}

// ---- P1: count edges per (bucket, block); no atomics to global ----
__global__ __launch_bounds__(NTHREADS) void p1_count_kernel(const int* __restrict__ dst,
                                                            unsigned int* __restrict__ cnt2d,
                                                            int nE, int nbuckets, int chunk) {
    __shared__ unsigned int hist[256];
    const int blk = blockIdx.x;
    const int t = threadIdx.x;
    hist[t] = 0;
    __syncthreads();
    const int e0 = blk * chunk;
    const int e1 = min(nE, e0 + chunk);
    for (int e = e0 + t; e < e1; e += NTHREADS)
        atomicAdd(&hist[dst[e] >> BSHIFT], 1u);
    __syncthreads();
    if (t < nbuckets) cnt2d[(size_t)t * NBP + blk] = hist[t];
}

// ---- exclusive scan (3 kernels) ----
__global__ __launch_bounds__(NTHREADS) void scan1_kernel(const unsigned int* __restrict__ in,
                                                         unsigned int* __restrict__ outv,
                                                         unsigned int* __restrict__ bsum, int n) {
    __shared__ unsigned int tmp[NTHREADS];
    const int base = blockIdx.x * SCAN_CHUNK;
    const int t = threadIdx.x;
    unsigned int v[4];
    #pragma unroll
    for (int k = 0; k < 4; ++k) {
        int i = base + t * 4 + k;
        v[k] = (i < n) ? in[i] : 0u;
    }
    unsigned int s = v[0] + v[1] + v[2] + v[3];
    tmp[t] = s;
    __syncthreads();
    for (int off = 1; off < NTHREADS; off <<= 1) {
        unsigned int val = (t >= off) ? tmp[t - off] : 0u;
        __syncthreads();
        tmp[t] += val;
        __syncthreads();
    }
    unsigned int excl = tmp[t] - s;
    if (t == NTHREADS - 1) bsum[blockIdx.x] = tmp[NTHREADS - 1];
    unsigned int run = excl;
    #pragma unroll
    for (int k = 0; k < 4; ++k) {
        int i = base + t * 4 + k;
        if (i < n) outv[i] = run;
        run += v[k];
    }
}

__global__ __launch_bounds__(NTHREADS) void scan2_kernel(unsigned int* __restrict__ bsum, int nb) {
    __shared__ unsigned int tmp[NTHREADS];
    int t = threadIdx.x;
    unsigned int v = (t < nb) ? bsum[t] : 0u;
    tmp[t] = v;
    __syncthreads();
    for (int off = 1; off < NTHREADS; off <<= 1) {
        unsigned int val = (t >= off) ? tmp[t - off] : 0u;
        __syncthreads();
        tmp[t] += val;
        __syncthreads();
    }
    if (t < nb) bsum[t] = tmp[t] - v;  // exclusive
}

__global__ __launch_bounds__(NTHREADS) void scan3_kernel(unsigned int* __restrict__ outv,
                                                         const unsigned int* __restrict__ bsum, int n) {
    int i = blockIdx.x * NTHREADS + threadIdx.x;
    if (i < n) outv[i] += bsum[i / SCAN_CHUNK];
}

// ---- P2: scatter (dst, meta) pairs into bucket regions; LDS slot alloc only ----
__global__ __launch_bounds__(NTHREADS) void p2_scatter_kernel(const int* __restrict__ src,
                                                              const int* __restrict__ dst,
                                                              const float* __restrict__ ew,
                                                              const unsigned int* __restrict__ base2d,
                                                              int2* __restrict__ pairs,
                                                              int nE, int nbuckets, int chunk) {
    __shared__ unsigned int fill[256];
    const int blk = blockIdx.x;
    const int t = threadIdx.x;
    if (t < nbuckets) fill[t] = base2d[(size_t)t * NBP + blk];
    __syncthreads();
    const int e0 = blk * chunk;
    const int e1 = min(nE, e0 + chunk);
    for (int e = e0 + t; e < e1; e += NTHREADS) {
        int d = dst[e];
        int s = src[e];
        unsigned int q = (unsigned int)(ew[e] * 32768.0f + 0.5f);
        q = q > 32767u ? 32767u : q;
        unsigned int m = ((unsigned int)s << 15) | q;
        unsigned int pos = atomicAdd(&fill[d >> BSHIFT], 1u);
        pairs[pos] = make_int2(d, (int)m);
    }
}

// ---- P3: per-bucket local CSR: rowptr, dinv, final meta ----
__global__ __launch_bounds__(1024) void p3_csr_kernel(const int2* __restrict__ pairs,
                                                      const unsigned int* __restrict__ base2d,
                                                      unsigned int* __restrict__ meta,
                                                      int* __restrict__ rowptr,
                                                      float* __restrict__ dinv,
                                                      int n, int nE, int nbuckets) {
    __shared__ unsigned int cnt[512];
    __shared__ unsigned int wsum[512];
    __shared__ unsigned int sc[512];
    __shared__ unsigned int fillL[512];
    const int b = blockIdx.x;
    const int t = threadIdx.x;
    const int node0 = b << BSHIFT;
    const int nloc = min(512, n - node0);
    const unsigned int e0 = base2d[(size_t)b * NBP];
    const unsigned int e1 = (b + 1 < nbuckets) ? base2d[(size_t)(b + 1) * NBP] : (unsigned int)nE;

    if (t < 512) { cnt[t] = 0u; wsum[t] = 0u; }
    __syncthreads();

    for (unsigned int e = e0 + t; e < e1; e += 1024) {
        int2 p = pairs[e];
        int dl = p.x & 511;
        atomicAdd(&cnt[dl], 1u);
        atomicAdd(&wsum[dl], (unsigned int)(p.y & 32767));
    }
    __syncthreads();

    if (t < 512) sc[t] = cnt[t];
    __syncthreads();
    for (int off = 1; off < 512; off <<= 1) {
        unsigned int v = (t >= off && t < 512) ? sc[t - off] : 0u;
        __syncthreads();
        if (t < 512) sc[t] += v;
        __syncthreads();
    }
    if (t < nloc) {
        unsigned int ex = sc[t] - cnt[t];   // exclusive scan
        rowptr[node0 + t] = (int)(e0 + ex);
        fillL[t] = ex;
        dinv[node0 + t] = rsqrtf(1.0f + (float)wsum[t] * (1.0f / 32768.0f));
    }
    if (b == nbuckets - 1 && t == 0) rowptr[n] = nE;
    __syncthreads();

    for (unsigned int e = e0 + t; e < e1; e += 1024) {
        int2 p = pairs[e];
        int dl = p.x & 511;
        unsigned int pos = e0 + atomicAdd(&fillL[dl], 1u);
        meta[pos] = (unsigned int)p.y;
    }
}

// ---- GEMM1: g1[n][64] = bf16(dinv[row] * (x[n][256] @ W1[256][64])) ----
// 128x64 tile, 256 threads, 8x4 outputs/thread, K-chunk 32.
__global__ __launch_bounds__(NTHREADS) void gemm1_kernel(const float* __restrict__ x,
                                                         const float* __restrict__ W,
                                                         const float* __restrict__ dinv,
                                                         unsigned short* __restrict__ g, int n) {
    __shared__ float xT[32][132];   // [k][row], pad for conflict-free
    __shared__ float ws[32][64];    // [k][col]
    const int t = threadIdx.x;
    const int row0 = blockIdx.x * 128;
    const int tc4 = (t & 15) * 4;   // output cols
    const int tr8 = (t >> 4) * 8;   // output rows
    const int kq = (t & 7) * 4;     // staging: k-quad within chunk
    const int rsub = t >> 3;        // staging: row within 32-row pass
    float acc[8][4] = {};

    for (int kb = 0; kb < 256; kb += 32) {
        #pragma unroll
        for (int p = 0; p < 4; ++p) {
            int r = p * 32 + rsub;
            int grow = row0 + r;
            float4 v = make_float4(0.f, 0.f, 0.f, 0.f);
            if (grow < n) v = *(const float4*)&x[(size_t)grow * 256 + kb + kq];
            xT[kq + 0][r] = v.x; xT[kq + 1][r] = v.y;
            xT[kq + 2][r] = v.z; xT[kq + 3][r] = v.w;
        }
        #pragma unroll
        for (int p = 0; p < 2; ++p) {
            int k = p * 16 + (t >> 4);
            *(float4*)&ws[k][tc4] = *(const float4*)&W[(size_t)(kb + k) * 64 + tc4];
        }
        __syncthreads();
        #pragma unroll
        for (int kk = 0; kk < 32; ++kk) {
            float4 wv = *(const float4*)&ws[kk][tc4];
            float4 xa = *(const float4*)&xT[kk][tr8];
            float4 xb = *(const float4*)&xT[kk][tr8 + 4];
            float xr[8] = {xa.x, xa.y, xa.z, xa.w, xb.x, xb.y, xb.z, xb.w};
            #pragma unroll
            for (int r = 0; r < 8; ++r) {
                acc[r][0] = fmaf(xr[r], wv.x, acc[r][0]);
                acc[r][1] = fmaf(xr[r], wv.y, acc[r][1]);
                acc[r][2] = fmaf(xr[r], wv.z, acc[r][2]);
                acc[r][3] = fmaf(xr[r], wv.w, acc[r][3]);
            }
        }
        __syncthreads();
    }
    #pragma unroll
    for (int r = 0; r < 8; ++r) {
        int grow = row0 + tr8 + r;
        if (grow < n) {
            float di = dinv[grow];
            ushort4 o;
            o.x = f2bf(di * acc[r][0]); o.y = f2bf(di * acc[r][1]);
            o.z = f2bf(di * acc[r][2]); o.w = f2bf(di * acc[r][3]);
            *(ushort4*)&g[(size_t)grow * 64 + tc4] = o;
        }
    }
}

// ---- agg1: wave-per-node, 16 lanes x 4 feats, 4-way edge split; bf16 gathers ----
// y1 = relu(dinv_d * (sum ew*g1[src] + g1[d]) + b1)
__global__ __launch_bounds__(NTHREADS) void agg1_csr_kernel(const int* __restrict__ rowptr,
                                                            const unsigned int* __restrict__ meta,
                                                            const unsigned short* __restrict__ g1,
                                                            const float* __restrict__ dinv,
                                                            const float* __restrict__ b1,
                                                            float* __restrict__ y1, int n) {
    const int wid = (blockIdx.x * NTHREADS + threadIdx.x) >> 6;  // node
    if (wid >= n) return;
    const int l = threadIdx.x & 63;
    const int fg = l & 15, eg = l >> 4;
    const int j4 = fg * 4;
    const int beg = rowptr[wid], end = rowptr[wid + 1];
    const float di = dinv[wid];
    const ushort4 su = *(const ushort4*)&g1[(size_t)wid * 64 + j4];

    float4 acc = make_float4(0.f, 0.f, 0.f, 0.f);
    int k = beg + eg;
    for (; k + 4 < end; k += 8) {
        unsigned int m0 = meta[k];
        unsigned int m1 = meta[k + 4];
        ushort4 u0 = *(const ushort4*)&g1[(size_t)(m0 >> 15) * 64 + j4];
        ushort4 u1 = *(const ushort4*)&g1[(size_t)(m1 >> 15) * 64 + j4];
        float w0 = (float)(m0 & 32767u) * (1.0f / 32768.0f);
        float w1 = (float)(m1 & 32767u) * (1.0f / 32768.0f);
        acc.x = fmaf(w0, bf2f(u0.x), acc.x); acc.y = fmaf(w0, bf2f(u0.y), acc.y);
        acc.z = fmaf(w0, bf2f(u0.z), acc.z); acc.w = fmaf(w0, bf2f(u0.w), acc.w);
        acc.x = fmaf(w1, bf2f(u1.x), acc.x); acc.y = fmaf(w1, bf2f(u1.y), acc.y);
        acc.z = fmaf(w1, bf2f(u1.z), acc.z); acc.w = fmaf(w1, bf2f(u1.w), acc.w);
    }
    if (k < end) {
        unsigned int m = meta[k];
        ushort4 u = *(const ushort4*)&g1[(size_t)(m >> 15) * 64 + j4];
        float w = (float)(m & 32767u) * (1.0f / 32768.0f);
        acc.x = fmaf(w, bf2f(u.x), acc.x); acc.y = fmaf(w, bf2f(u.y), acc.y);
        acc.z = fmaf(w, bf2f(u.z), acc.z); acc.w = fmaf(w, bf2f(u.w), acc.w);
    }
    #pragma unroll
    for (int m = 16; m <= 32; m <<= 1) {
        acc.x += __shfl_xor(acc.x, m);
        acc.y += __shfl_xor(acc.y, m);
        acc.z += __shfl_xor(acc.z, m);
        acc.w += __shfl_xor(acc.w, m);
    }
    if (eg == 0) {
        float4 bb = *(const float4*)&b1[j4];
        float4 r;
        r.x = fmaxf(fmaf(di, acc.x + bf2f(su.x), bb.x), 0.f);
        r.y = fmaxf(fmaf(di, acc.y + bf2f(su.y), bb.y), 0.f);
        r.z = fmaxf(fmaf(di, acc.z + bf2f(su.z), bb.z), 0.f);
        r.w = fmaxf(fmaf(di, acc.w + bf2f(su.w), bb.w), 0.f);
        *(float4*)&y1[(size_t)wid * 64 + j4] = r;
    }
}

// ---- GEMM2: g2[n][32] = bf16(dinv[row] * (y1[n][64] @ W2[64][32])) ----
__global__ __launch_bounds__(NTHREADS) void gemm2_kernel(const float* __restrict__ y1,
                                                         const float* __restrict__ W,
                                                         const float* __restrict__ dinv,
                                                         unsigned short* __restrict__ g, int n) {
    __shared__ float xT[64][68];
    __shared__ float ws[64][32];
    const int t = threadIdx.x;
    const int row0 = blockIdx.x * 64;
    const int tc2 = (t & 15) * 2;
    const int tr4 = (t >> 4) * 4;
    float acc[4][2] = {};

    const int tx = t & 63;
    const int ty = t >> 6;
    #pragma unroll
    for (int rp = 0; rp < 16; ++rp) {
        int r = ty * 16 + rp;
        int grow = row0 + r;
        float v = (grow < n) ? y1[(size_t)grow * 64 + tx] : 0.0f;
        xT[tx][r] = v;
    }
    #pragma unroll
    for (int p = 0; p < 8; ++p) {
        int idx = p * 256 + t;
        ws[idx >> 5][idx & 31] = W[idx];
    }
    __syncthreads();
    #pragma unroll
    for (int kk = 0; kk < 64; ++kk) {
        float4 xv = *(const float4*)&xT[kk][tr4];
        float2 wv = *(const float2*)&ws[kk][tc2];
        acc[0][0] += xv.x * wv.x; acc[0][1] += xv.x * wv.y;
        acc[1][0] += xv.y * wv.x; acc[1][1] += xv.y * wv.y;
        acc[2][0] += xv.z * wv.x; acc[2][1] += xv.z * wv.y;
        acc[3][0] += xv.w * wv.x; acc[3][1] += xv.w * wv.y;
    }
    #pragma unroll
    for (int r = 0; r < 4; ++r) {
        int grow = row0 + tr4 + r;
        if (grow < n) {
            float di = dinv[grow];
            ushort2 o;
            o.x = f2bf(di * acc[r][0]); o.y = f2bf(di * acc[r][1]);
            *(ushort2*)&g[(size_t)grow * 32 + tc2] = o;
        }
    }
}

// ---- agg2: wave-per-node, 8 lanes x 4 feats, 8-way edge split, LDS pool; bf16 gathers ----
__global__ __launch_bounds__(NTHREADS) void agg2_csr_pool_kernel(const int* __restrict__ rowptr,
                                                                 const unsigned int* __restrict__ meta,
                                                                 const unsigned short* __restrict__ g2,
                                                                 const float* __restrict__ dinv,
                                                                 const float* __restrict__ b2,
                                                                 const int* __restrict__ batch,
                                                                 unsigned int* __restrict__ pooled,
                                                                 int n) {
    __shared__ float smax[4][32];
    __shared__ int sb[4];
    const int w = threadIdx.x >> 6;            // wave in block
    const int l = threadIdx.x & 63;
    const int node = blockIdx.x * 4 + w;
    const bool active = node < n;
    const int fg = l & 7, eg = l >> 3;
    const int j4 = fg * 4;

    if (l == 0) sb[w] = active ? batch[node] : -1;

    if (active) {
        const int beg = rowptr[node], end = rowptr[node + 1];
        const float di = dinv[node];
        const ushort4 su = *(const ushort4*)&g2[(size_t)node * 32 + j4];

        float4 acc = make_float4(0.f, 0.f, 0.f, 0.f);
        int k = beg + eg;
        for (; k + 8 < end; k += 16) {
            unsigned int m0 = meta[k];
            unsigned int m1 = meta[k + 8];
            ushort4 u0 = *(const ushort4*)&g2[(size_t)(m0 >> 15) * 32 + j4];
            ushort4 u1 = *(const ushort4*)&g2[(size_t)(m1 >> 15) * 32 + j4];
            float w0 = (float)(m0 & 32767u) * (1.0f / 32768.0f);
            float w1 = (float)(m1 & 32767u) * (1.0f / 32768.0f);
            acc.x = fmaf(w0, bf2f(u0.x), acc.x); acc.y = fmaf(w0, bf2f(u0.y), acc.y);
            acc.z = fmaf(w0, bf2f(u0.z), acc.z); acc.w = fmaf(w0, bf2f(u0.w), acc.w);
            acc.x = fmaf(w1, bf2f(u1.x), acc.x); acc.y = fmaf(w1, bf2f(u1.y), acc.y);
            acc.z = fmaf(w1, bf2f(u1.z), acc.z); acc.w = fmaf(w1, bf2f(u1.w), acc.w);
        }
        if (k < end) {
            unsigned int m = meta[k];
            ushort4 u = *(const ushort4*)&g2[(size_t)(m >> 15) * 32 + j4];
            float wq = (float)(m & 32767u) * (1.0f / 32768.0f);
            acc.x = fmaf(wq, bf2f(u.x), acc.x); acc.y = fmaf(wq, bf2f(u.y), acc.y);
            acc.z = fmaf(wq, bf2f(u.z), acc.z); acc.w = fmaf(wq, bf2f(u.w), acc.w);
        }
        #pragma unroll
        for (int m = 8; m <= 32; m <<= 1) {
            acc.x += __shfl_xor(acc.x, m);
            acc.y += __shfl_xor(acc.y, m);
            acc.z += __shfl_xor(acc.z, m);
            acc.w += __shfl_xor(acc.w, m);
        }
        if (eg == 0) {
            float4 bb = *(const float4*)&b2[j4];
            float4 r;
            r.x = fmaxf(fmaf(di, acc.x + bf2f(su.x), bb.x), 0.f);
            r.y = fmaxf(fmaf(di, acc.y + bf2f(su.y), bb.y), 0.f);
            r.z = fmaxf(fmaf(di, acc.z + bf2f(su.z), bb.z), 0.f);
            r.w = fmaxf(fmaf(di, acc.w + bf2f(su.w), bb.w), 0.f);
            *(float4*)&smax[w][j4] = r;
        }
    }
    __syncthreads();
    const int t = threadIdx.x;
    if (t < 32) {
        int b0 = sb[0], b1_ = sb[1], b2_ = sb[2], b3_ = sb[3];
        if (b0 >= 0 && b0 == b1_ && b0 == b2_ && b0 == b3_) {
            float v = fmaxf(fmaxf(smax[0][t], smax[1][t]), fmaxf(smax[2][t], smax[3][t]));
            atomicMax(&pooled[b0 * 32 + t], __float_as_uint(v));
        } else {
            #pragma unroll
            for (int ww = 0; ww < 4; ++ww) {
                if (sb[ww] >= 0)
                    atomicMax(&pooled[sb[ww] * 32 + t], __float_as_uint(smax[ww][t]));
            }
        }
    }
}

// ---------------- final: out[64][4] = pooled[64][32] @ Wlin[32][4] + blin ----------------
__global__ __launch_bounds__(NTHREADS) void final_kernel(const float* __restrict__ pooled,
                                                         const float* __restrict__ Wlin,
                                                         const float* __restrict__ blin,
                                                         float* __restrict__ out) {
    int t = threadIdx.x;  // 256 = 64 graphs * 4 cols
    int g = t >> 2, c = t & 3;
    float s = blin[c];
    #pragma unroll
    for (int j = 0; j < 32; ++j) s += pooled[g * 32 + j] * Wlin[j * 4 + c];
    out[g * 4 + c] = s;
}

extern "C" void kernel_launch(void* const* d_in, const int* in_sizes, int n_in,
                              void* d_out, int out_size, void* d_ws, size_t ws_size,
                              hipStream_t stream) {
    const float* x     = (const float*)d_in[0];
    const int*   ei    = (const int*)d_in[1];
    const float* ew    = (const float*)d_in[2];
    const int*   batch = (const int*)d_in[3];
    const float* W1    = (const float*)d_in[4];
    const float* b1    = (const float*)d_in[5];
    const float* W2    = (const float*)d_in[6];
    const float* b2    = (const float*)d_in[7];
    const float* Wlin  = (const float*)d_in[8];
    const float* blin  = (const float*)d_in[9];
    float* out = (float*)d_out;

    const int E = in_sizes[2];   // 3200000
    const int n = in_sizes[3];   // 100000
    const int* src = ei;
    const int* dst = ei + E;

    const int nbuckets = (n + 511) >> BSHIFT;            // 196
    const int chunk = (E + NBP - 1) / NBP;               // 6250
    const int scanlen = nbuckets * NBP;                  // 100352
    const int nchunks = (scanlen + SCAN_CHUNK - 1) / SCAN_CHUNK;  // 98

    // workspace layout (4-byte units)
    auto al = [](size_t v) { return (v + 63) & ~(size_t)63; };
    float* ws = (float*)d_ws;
    size_t off = 0;
    unsigned int* cnt2d  = (unsigned int*)(ws + off); off += al(scanlen);
    unsigned int* base2d = (unsigned int*)(ws + off); off += al(scanlen);
    unsigned int* bsum   = (unsigned int*)(ws + off); off += al(256);
    float* dinv    = ws + off; off += al(n);
    int*   rowptr  = (int*)(ws + off); off += al(n + 1);
    unsigned int* meta = (unsigned int*)(ws + off); off += al(E);
    unsigned short* g1 = (unsigned short*)(ws + off); off += al((size_t)n * 32);  // bf16 n*64
    float* y1      = ws + off; off += al((size_t)n * 64);   // ALSO aliases pairs (dead after P3)
    float* pooled  = ws + off; off += al(64 * 32);
    unsigned short* g2 = g1;    // g1 dead after agg1; gemm2 overwrites with g2 (bf16 n*32)
    int2*  pairs = (int2*)y1;   // E*8 bytes == n*64*4 bytes; pairs dead before agg1 writes y1

    hipMemsetAsync(pooled, 0, 64 * 32 * sizeof(float), stream);

    // CSR build (no global atomics)
    p1_count_kernel<<<NBP, NTHREADS, 0, stream>>>(dst, cnt2d, E, nbuckets, chunk);
    scan1_kernel<<<nchunks, NTHREADS, 0, stream>>>(cnt2d, base2d, bsum, scanlen);
    scan2_kernel<<<1, NTHREADS, 0, stream>>>(bsum, nchunks);
    scan3_kernel<<<(scanlen + 255) / 256, NTHREADS, 0, stream>>>(base2d, bsum, scanlen);
    p2_scatter_kernel<<<NBP, NTHREADS, 0, stream>>>(src, dst, ew, base2d, pairs, E, nbuckets, chunk);
    p3_csr_kernel<<<nbuckets, 1024, 0, stream>>>(pairs, base2d, meta, rowptr, dinv, n, E, nbuckets);

    // layer 1
    gemm1_kernel<<<(n + 127) / 128, NTHREADS, 0, stream>>>(x, W1, dinv, g1, n);
    agg1_csr_kernel<<<(n + 3) / 4, NTHREADS, 0, stream>>>(rowptr, meta, g1, dinv, b1, y1, n);

    // layer 2
    gemm2_kernel<<<(n + 63) / 64, NTHREADS, 0, stream>>>(y1, W2, dinv, g2, n);
    agg2_csr_pool_kernel<<<(n + 3) / 4, NTHREADS, 0, stream>>>(
        rowptr, meta, g2, dinv, b2, batch, (unsigned int*)pooled, n);

    final_kernel<<<1, NTHREADS, 0, stream>>>(pooled, Wlin, blin, out);
}

// Round 10
// 480.085 us; speedup vs baseline: 3.5111x; 1.0482x over previous
//
#include <hip/hip_runtime.h>
#include <hip/hip_bf16.h>

// GCN: 2x GCNConv (sym-norm, self-loops) + ReLU, segment_max pool, linear.
// N=100000, E=3200000, G=64, IN=256, H1=64, H2=32.
// CSR build with ZERO global atomics (counting sort P1/scan/P2/P3).
// P2 is LDS-staged: pairs ordered by bucket in LDS, flushed coalesced.
// meta = (src<<15)|q15(ew). GEMMs write g = bf16(dinv*.(X@W)); y1 also bf16.
// aggs: relu(dinv_d*(sum ew*g[src] + g[d]) + b) in fp32, unroll-4 gathers.

#define NTHREADS 256
#define SCAN_CHUNK 1024
#define NBP 512           // blocks in P1/P2
#define BSHIFT 9          // bucket = dst >> 9 (512 nodes/bucket)
#define MAXCHUNK 6272     // >= (E+NBP-1)/NBP = 6250

__device__ __forceinline__ unsigned short f2bf(float f) {
    unsigned int u = __float_as_uint(f);
    u = (u + 0x7FFFu + ((u >> 16) & 1u)) >> 16;   // round-to-nearest-even
    return (unsigned short)u;
}
__device__ __forceinline__ float bf2f(unsigned short s) {
    return __uint_as_float((unsigned int)s << 16);
}

// ---- P1: count edges per (bucket, block); no atomics to global ----
__global__ __launch_bounds__(NTHREADS) void p1_count_kernel(const int* __restrict__ dst,
                                                            unsigned int* __restrict__ cnt2d,
                                                            int nE, int nbuckets, int chunk) {
    __shared__ unsigned int hist[256];
    const int blk = blockIdx.x;
    const int t = threadIdx.x;
    hist[t] = 0;
    __syncthreads();
    const int e0 = blk * chunk;
    const int e1 = min(nE, e0 + chunk);
    for (int e = e0 + t; e < e1; e += NTHREADS)
        atomicAdd(&hist[dst[e] >> BSHIFT], 1u);
    __syncthreads();
    if (t < nbuckets) cnt2d[(size_t)t * NBP + blk] = hist[t];
}

// ---- exclusive scan (3 kernels) ----
__global__ __launch_bounds__(NTHREADS) void scan1_kernel(const unsigned int* __restrict__ in,
                                                         unsigned int* __restrict__ outv,
                                                         unsigned int* __restrict__ bsum, int n) {
    __shared__ unsigned int tmp[NTHREADS];
    const int base = blockIdx.x * SCAN_CHUNK;
    const int t = threadIdx.x;
    unsigned int v[4];
    #pragma unroll
    for (int k = 0; k < 4; ++k) {
        int i = base + t * 4 + k;
        v[k] = (i < n) ? in[i] : 0u;
    }
    unsigned int s = v[0] + v[1] + v[2] + v[3];
    tmp[t] = s;
    __syncthreads();
    for (int off = 1; off < NTHREADS; off <<= 1) {
        unsigned int val = (t >= off) ? tmp[t - off] : 0u;
        __syncthreads();
        tmp[t] += val;
        __syncthreads();
    }
    unsigned int excl = tmp[t] - s;
    if (t == NTHREADS - 1) bsum[blockIdx.x] = tmp[NTHREADS - 1];
    unsigned int run = excl;
    #pragma unroll
    for (int k = 0; k < 4; ++k) {
        int i = base + t * 4 + k;
        if (i < n) outv[i] = run;
        run += v[k];
    }
}

__global__ __launch_bounds__(NTHREADS) void scan2_kernel(unsigned int* __restrict__ bsum, int nb) {
    __shared__ unsigned int tmp[NTHREADS];
    int t = threadIdx.x;
    unsigned int v = (t < nb) ? bsum[t] : 0u;
    tmp[t] = v;
    __syncthreads();
    for (int off = 1; off < NTHREADS; off <<= 1) {
        unsigned int val = (t >= off) ? tmp[t - off] : 0u;
        __syncthreads();
        tmp[t] += val;
        __syncthreads();
    }
    if (t < nb) bsum[t] = tmp[t] - v;  // exclusive
}

__global__ __launch_bounds__(NTHREADS) void scan3_kernel(unsigned int* __restrict__ outv,
                                                         const unsigned int* __restrict__ bsum, int n) {
    int i = blockIdx.x * NTHREADS + threadIdx.x;
    if (i < n) outv[i] += bsum[i / SCAN_CHUNK];
}

// ---- P2: LDS-staged scatter: stage pairs bucket-ordered, flush coalesced ----
__global__ __launch_bounds__(NTHREADS) void p2_scatter_kernel(const int* __restrict__ src,
                                                              const int* __restrict__ dst,
                                                              const float* __restrict__ ew,
                                                              const unsigned int* __restrict__ cnt2d,
                                                              const unsigned int* __restrict__ base2d,
                                                              int2* __restrict__ pairs,
                                                              int nE, int nbuckets, int chunk) {
    __shared__ int2 stage[MAXCHUNK];            // 50.2 KB
    __shared__ unsigned char stgb[MAXCHUNK];    // 6.3 KB
    __shared__ unsigned int lofs[256];
    __shared__ unsigned int fill[256];
    __shared__ unsigned int gbase[256];
    const int blk = blockIdx.x;
    const int t = threadIdx.x;

    // local exclusive scan of this block's bucket counts
    unsigned int c = (t < nbuckets) ? cnt2d[(size_t)t * NBP + blk] : 0u;
    lofs[t] = c;
    if (t < nbuckets) gbase[t] = base2d[(size_t)t * NBP + blk];
    __syncthreads();
    for (int off = 1; off < NTHREADS; off <<= 1) {
        unsigned int val = (t >= off) ? lofs[t - off] : 0u;
        __syncthreads();
        lofs[t] += val;
        __syncthreads();
    }
    // lofs now inclusive; convert to exclusive
    unsigned int ex = lofs[t] - c;
    __syncthreads();
    lofs[t] = ex;
    fill[t] = ex;
    __syncthreads();

    // pass 1: stage pairs into LDS at bucket-ordered slots
    const int e0 = blk * chunk;
    const int e1 = min(nE, e0 + chunk);
    for (int e = e0 + t; e < e1; e += NTHREADS) {
        int d = dst[e];
        int s = src[e];
        int b = d >> BSHIFT;
        unsigned int q = (unsigned int)(ew[e] * 32768.0f + 0.5f);
        q = q > 32767u ? 32767u : q;
        unsigned int m = ((unsigned int)s << 15) | q;
        unsigned int slot = atomicAdd(&fill[b], 1u);
        stage[slot] = make_int2(d, (int)m);
        stgb[slot] = (unsigned char)b;
    }
    __syncthreads();

    // pass 2: linear LDS -> global (bucket-ordered => coalesced runs)
    const int total = e1 - e0;
    for (int i = t; i < total; i += NTHREADS) {
        int b = stgb[i];
        unsigned int gpos = gbase[b] + ((unsigned int)i - lofs[b]);
        pairs[gpos] = stage[i];
    }
}

// ---- P3: per-bucket local CSR: rowptr, dinv, final meta ----
__global__ __launch_bounds__(1024) void p3_csr_kernel(const int2* __restrict__ pairs,
                                                      const unsigned int* __restrict__ base2d,
                                                      unsigned int* __restrict__ meta,
                                                      int* __restrict__ rowptr,
                                                      float* __restrict__ dinv,
                                                      int n, int nE, int nbuckets) {
    __shared__ unsigned int cnt[512];
    __shared__ unsigned int wsum[512];
    __shared__ unsigned int sc[512];
    __shared__ unsigned int fillL[512];
    const int b = blockIdx.x;
    const int t = threadIdx.x;
    const int node0 = b << BSHIFT;
    const int nloc = min(512, n - node0);
    const unsigned int e0 = base2d[(size_t)b * NBP];
    const unsigned int e1 = (b + 1 < nbuckets) ? base2d[(size_t)(b + 1) * NBP] : (unsigned int)nE;

    if (t < 512) { cnt[t] = 0u; wsum[t] = 0u; }
    __syncthreads();

    for (unsigned int e = e0 + t; e < e1; e += 1024) {
        int2 p = pairs[e];
        int dl = p.x & 511;
        atomicAdd(&cnt[dl], 1u);
        atomicAdd(&wsum[dl], (unsigned int)(p.y & 32767));
    }
    __syncthreads();

    if (t < 512) sc[t] = cnt[t];
    __syncthreads();
    for (int off = 1; off < 512; off <<= 1) {
        unsigned int v = (t >= off && t < 512) ? sc[t - off] : 0u;
        __syncthreads();
        if (t < 512) sc[t] += v;
        __syncthreads();
    }
    if (t < nloc) {
        unsigned int ex = sc[t] - cnt[t];   // exclusive scan
        rowptr[node0 + t] = (int)(e0 + ex);
        fillL[t] = ex;
        dinv[node0 + t] = rsqrtf(1.0f + (float)wsum[t] * (1.0f / 32768.0f));
    }
    if (b == nbuckets - 1 && t == 0) rowptr[n] = nE;
    __syncthreads();

    for (unsigned int e = e0 + t; e < e1; e += 1024) {
        int2 p = pairs[e];
        int dl = p.x & 511;
        unsigned int pos = e0 + atomicAdd(&fillL[dl], 1u);
        meta[pos] = (unsigned int)p.y;
    }
}

// ---- GEMM1: g1[n][64] = bf16(dinv[row] * (x[n][256] @ W1[256][64])) ----
__global__ __launch_bounds__(NTHREADS) void gemm1_kernel(const float* __restrict__ x,
                                                         const float* __restrict__ W,
                                                         const float* __restrict__ dinv,
                                                         unsigned short* __restrict__ g, int n) {
    __shared__ float xT[32][132];
    __shared__ float ws[32][64];
    const int t = threadIdx.x;
    const int row0 = blockIdx.x * 128;
    const int tc4 = (t & 15) * 4;
    const int tr8 = (t >> 4) * 8;
    const int kq = (t & 7) * 4;
    const int rsub = t >> 3;
    float acc[8][4] = {};

    for (int kb = 0; kb < 256; kb += 32) {
        #pragma unroll
        for (int p = 0; p < 4; ++p) {
            int r = p * 32 + rsub;
            int grow = row0 + r;
            float4 v = make_float4(0.f, 0.f, 0.f, 0.f);
            if (grow < n) v = *(const float4*)&x[(size_t)grow * 256 + kb + kq];
            xT[kq + 0][r] = v.x; xT[kq + 1][r] = v.y;
            xT[kq + 2][r] = v.z; xT[kq + 3][r] = v.w;
        }
        #pragma unroll
        for (int p = 0; p < 2; ++p) {
            int k = p * 16 + (t >> 4);
            *(float4*)&ws[k][tc4] = *(const float4*)&W[(size_t)(kb + k) * 64 + tc4];
        }
        __syncthreads();
        #pragma unroll
        for (int kk = 0; kk < 32; ++kk) {
            float4 wv = *(const float4*)&ws[kk][tc4];
            float4 xa = *(const float4*)&xT[kk][tr8];
            float4 xb = *(const float4*)&xT[kk][tr8 + 4];
            float xr[8] = {xa.x, xa.y, xa.z, xa.w, xb.x, xb.y, xb.z, xb.w};
            #pragma unroll
            for (int r = 0; r < 8; ++r) {
                acc[r][0] = fmaf(xr[r], wv.x, acc[r][0]);
                acc[r][1] = fmaf(xr[r], wv.y, acc[r][1]);
                acc[r][2] = fmaf(xr[r], wv.z, acc[r][2]);
                acc[r][3] = fmaf(xr[r], wv.w, acc[r][3]);
            }
        }
        __syncthreads();
    }
    #pragma unroll
    for (int r = 0; r < 8; ++r) {
        int grow = row0 + tr8 + r;
        if (grow < n) {
            float di = dinv[grow];
            ushort4 o;
            o.x = f2bf(di * acc[r][0]); o.y = f2bf(di * acc[r][1]);
            o.z = f2bf(di * acc[r][2]); o.w = f2bf(di * acc[r][3]);
            *(ushort4*)&g[(size_t)grow * 64 + tc4] = o;
        }
    }
}

// ---- agg1: wave-per-node, 16 lanes x 4 feats, 4-way edge split, unroll 4; bf16 ----
// y1 (bf16) = relu(dinv_d * (sum ew*g1[src] + g1[d]) + b1)
__global__ __launch_bounds__(NTHREADS) void agg1_csr_kernel(const int* __restrict__ rowptr,
                                                            const unsigned int* __restrict__ meta,
                                                            const unsigned short* __restrict__ g1,
                                                            const float* __restrict__ dinv,
                                                            const float* __restrict__ b1,
                                                            unsigned short* __restrict__ y1, int n) {
    const int wid = (blockIdx.x * NTHREADS + threadIdx.x) >> 6;  // node
    if (wid >= n) return;
    const int l = threadIdx.x & 63;
    const int fg = l & 15, eg = l >> 4;
    const int j4 = fg * 4;
    const int beg = rowptr[wid], end = rowptr[wid + 1];
    const float di = dinv[wid];
    const ushort4 su = *(const ushort4*)&g1[(size_t)wid * 64 + j4];

    float4 acc = make_float4(0.f, 0.f, 0.f, 0.f);
    int k = beg + eg;
    for (; k + 12 < end; k += 16) {
        unsigned int m0 = meta[k];
        unsigned int m1 = meta[k + 4];
        unsigned int m2 = meta[k + 8];
        unsigned int m3 = meta[k + 12];
        ushort4 u0 = *(const ushort4*)&g1[(size_t)(m0 >> 15) * 64 + j4];
        ushort4 u1 = *(const ushort4*)&g1[(size_t)(m1 >> 15) * 64 + j4];
        ushort4 u2 = *(const ushort4*)&g1[(size_t)(m2 >> 15) * 64 + j4];
        ushort4 u3 = *(const ushort4*)&g1[(size_t)(m3 >> 15) * 64 + j4];
        float w0 = (float)(m0 & 32767u) * (1.0f / 32768.0f);
        float w1 = (float)(m1 & 32767u) * (1.0f / 32768.0f);
        float w2 = (float)(m2 & 32767u) * (1.0f / 32768.0f);
        float w3 = (float)(m3 & 32767u) * (1.0f / 32768.0f);
        acc.x = fmaf(w0, bf2f(u0.x), acc.x); acc.y = fmaf(w0, bf2f(u0.y), acc.y);
        acc.z = fmaf(w0, bf2f(u0.z), acc.z); acc.w = fmaf(w0, bf2f(u0.w), acc.w);
        acc.x = fmaf(w1, bf2f(u1.x), acc.x); acc.y = fmaf(w1, bf2f(u1.y), acc.y);
        acc.z = fmaf(w1, bf2f(u1.z), acc.z); acc.w = fmaf(w1, bf2f(u1.w), acc.w);
        acc.x = fmaf(w2, bf2f(u2.x), acc.x); acc.y = fmaf(w2, bf2f(u2.y), acc.y);
        acc.z = fmaf(w2, bf2f(u2.z), acc.z); acc.w = fmaf(w2, bf2f(u2.w), acc.w);
        acc.x = fmaf(w3, bf2f(u3.x), acc.x); acc.y = fmaf(w3, bf2f(u3.y), acc.y);
        acc.z = fmaf(w3, bf2f(u3.z), acc.z); acc.w = fmaf(w3, bf2f(u3.w), acc.w);
    }
    for (; k < end; k += 4) {
        unsigned int m = meta[k];
        ushort4 u = *(const ushort4*)&g1[(size_t)(m >> 15) * 64 + j4];
        float w = (float)(m & 32767u) * (1.0f / 32768.0f);
        acc.x = fmaf(w, bf2f(u.x), acc.x); acc.y = fmaf(w, bf2f(u.y), acc.y);
        acc.z = fmaf(w, bf2f(u.z), acc.z); acc.w = fmaf(w, bf2f(u.w), acc.w);
    }
    #pragma unroll
    for (int m = 16; m <= 32; m <<= 1) {
        acc.x += __shfl_xor(acc.x, m);
        acc.y += __shfl_xor(acc.y, m);
        acc.z += __shfl_xor(acc.z, m);
        acc.w += __shfl_xor(acc.w, m);
    }
    if (eg == 0) {
        float4 bb = *(const float4*)&b1[j4];
        ushort4 o;
        o.x = f2bf(fmaxf(fmaf(di, acc.x + bf2f(su.x), bb.x), 0.f));
        o.y = f2bf(fmaxf(fmaf(di, acc.y + bf2f(su.y), bb.y), 0.f));
        o.z = f2bf(fmaxf(fmaf(di, acc.z + bf2f(su.z), bb.z), 0.f));
        o.w = f2bf(fmaxf(fmaf(di, acc.w + bf2f(su.w), bb.w), 0.f));
        *(ushort4*)&y1[(size_t)wid * 64 + j4] = o;
    }
}

// ---- GEMM2: g2[n][32] = bf16(dinv[row] * (y1[n][64] @ W2[64][32])), y1 bf16 ----
__global__ __launch_bounds__(NTHREADS) void gemm2_kernel(const unsigned short* __restrict__ y1,
                                                         const float* __restrict__ W,
                                                         const float* __restrict__ dinv,
                                                         unsigned short* __restrict__ g, int n) {
    __shared__ float xT[64][68];
    __shared__ float ws[64][32];
    const int t = threadIdx.x;
    const int row0 = blockIdx.x * 64;
    const int tc2 = (t & 15) * 2;
    const int tr4 = (t >> 4) * 4;
    float acc[4][2] = {};

    const int tx = t & 63;
    const int ty = t >> 6;
    #pragma unroll
    for (int rp = 0; rp < 16; ++rp) {
        int r = ty * 16 + rp;
        int grow = row0 + r;
        float v = (grow < n) ? bf2f(y1[(size_t)grow * 64 + tx]) : 0.0f;
        xT[tx][r] = v;
    }
    #pragma unroll
    for (int p = 0; p < 8; ++p) {
        int idx = p * 256 + t;
        ws[idx >> 5][idx & 31] = W[idx];
    }
    __syncthreads();
    #pragma unroll
    for (int kk = 0; kk < 64; ++kk) {
        float4 xv = *(const float4*)&xT[kk][tr4];
        float2 wv = *(const float2*)&ws[kk][tc2];
        acc[0][0] += xv.x * wv.x; acc[0][1] += xv.x * wv.y;
        acc[1][0] += xv.y * wv.x; acc[1][1] += xv.y * wv.y;
        acc[2][0] += xv.z * wv.x; acc[2][1] += xv.z * wv.y;
        acc[3][0] += xv.w * wv.x; acc[3][1] += xv.w * wv.y;
    }
    #pragma unroll
    for (int r = 0; r < 4; ++r) {
        int grow = row0 + tr4 + r;
        if (grow < n) {
            float di = dinv[grow];
            ushort2 o;
            o.x = f2bf(di * acc[r][0]); o.y = f2bf(di * acc[r][1]);
            *(ushort2*)&g[(size_t)grow * 32 + tc2] = o;
        }
    }
}

// ---- agg2: wave-per-node, 8 lanes x 4 feats, 8-way edge split, unroll 4, LDS pool ----
__global__ __launch_bounds__(NTHREADS) void agg2_csr_pool_kernel(const int* __restrict__ rowptr,
                                                                 const unsigned int* __restrict__ meta,
                                                                 const unsigned short* __restrict__ g2,
                                                                 const float* __restrict__ dinv,
                                                                 const float* __restrict__ b2,
                                                                 const int* __restrict__ batch,
                                                                 unsigned int* __restrict__ pooled,
                                                                 int n) {
    __shared__ float smax[4][32];
    __shared__ int sb[4];
    const int w = threadIdx.x >> 6;
    const int l = threadIdx.x & 63;
    const int node = blockIdx.x * 4 + w;
    const bool active = node < n;
    const int fg = l & 7, eg = l >> 3;
    const int j4 = fg * 4;

    if (l == 0) sb[w] = active ? batch[node] : -1;

    if (active) {
        const int beg = rowptr[node], end = rowptr[node + 1];
        const float di = dinv[node];
        const ushort4 su = *(const ushort4*)&g2[(size_t)node * 32 + j4];

        float4 acc = make_float4(0.f, 0.f, 0.f, 0.f);
        int k = beg + eg;
        for (; k + 24 < end; k += 32) {
            unsigned int m0 = meta[k];
            unsigned int m1 = meta[k + 8];
            unsigned int m2 = meta[k + 16];
            unsigned int m3 = meta[k + 24];
            ushort4 u0 = *(const ushort4*)&g2[(size_t)(m0 >> 15) * 32 + j4];
            ushort4 u1 = *(const ushort4*)&g2[(size_t)(m1 >> 15) * 32 + j4];
            ushort4 u2 = *(const ushort4*)&g2[(size_t)(m2 >> 15) * 32 + j4];
            ushort4 u3 = *(const ushort4*)&g2[(size_t)(m3 >> 15) * 32 + j4];
            float w0 = (float)(m0 & 32767u) * (1.0f / 32768.0f);
            float w1 = (float)(m1 & 32767u) * (1.0f / 32768.0f);
            float w2 = (float)(m2 & 32767u) * (1.0f / 32768.0f);
            float w3 = (float)(m3 & 32767u) * (1.0f / 32768.0f);
            acc.x = fmaf(w0, bf2f(u0.x), acc.x); acc.y = fmaf(w0, bf2f(u0.y), acc.y);
            acc.z = fmaf(w0, bf2f(u0.z), acc.z); acc.w = fmaf(w0, bf2f(u0.w), acc.w);
            acc.x = fmaf(w1, bf2f(u1.x), acc.x); acc.y = fmaf(w1, bf2f(u1.y), acc.y);
            acc.z = fmaf(w1, bf2f(u1.z), acc.z); acc.w = fmaf(w1, bf2f(u1.w), acc.w);
            acc.x = fmaf(w2, bf2f(u2.x), acc.x); acc.y = fmaf(w2, bf2f(u2.y), acc.y);
            acc.z = fmaf(w2, bf2f(u2.z), acc.z); acc.w = fmaf(w2, bf2f(u2.w), acc.w);
            acc.x = fmaf(w3, bf2f(u3.x), acc.x); acc.y = fmaf(w3, bf2f(u3.y), acc.y);
            acc.z = fmaf(w3, bf2f(u3.z), acc.z); acc.w = fmaf(w3, bf2f(u3.w), acc.w);
        }
        for (; k < end; k += 8) {
            unsigned int m = meta[k];
            ushort4 u = *(const ushort4*)&g2[(size_t)(m >> 15) * 32 + j4];
            float wq = (float)(m & 32767u) * (1.0f / 32768.0f);
            acc.x = fmaf(wq, bf2f(u.x), acc.x); acc.y = fmaf(wq, bf2f(u.y), acc.y);
            acc.z = fmaf(wq, bf2f(u.z), acc.z); acc.w = fmaf(wq, bf2f(u.w), acc.w);
        }
        #pragma unroll
        for (int m = 8; m <= 32; m <<= 1) {
            acc.x += __shfl_xor(acc.x, m);
            acc.y += __shfl_xor(acc.y, m);
            acc.z += __shfl_xor(acc.z, m);
            acc.w += __shfl_xor(acc.w, m);
        }
        if (eg == 0) {
            float4 bb = *(const float4*)&b2[j4];
            float4 r;
            r.x = fmaxf(fmaf(di, acc.x + bf2f(su.x), bb.x), 0.f);
            r.y = fmaxf(fmaf(di, acc.y + bf2f(su.y), bb.y), 0.f);
            r.z = fmaxf(fmaf(di, acc.z + bf2f(su.z), bb.z), 0.f);
            r.w = fmaxf(fmaf(di, acc.w + bf2f(su.w), bb.w), 0.f);
            *(float4*)&smax[w][j4] = r;
        }
    }
    __syncthreads();
    const int t = threadIdx.x;
    if (t < 32) {
        int b0 = sb[0], b1_ = sb[1], b2_ = sb[2], b3_ = sb[3];
        if (b0 >= 0 && b0 == b1_ && b0 == b2_ && b0 == b3_) {
            float v = fmaxf(fmaxf(smax[0][t], smax[1][t]), fmaxf(smax[2][t], smax[3][t]));
            atomicMax(&pooled[b0 * 32 + t], __float_as_uint(v));
        } else {
            #pragma unroll
            for (int ww = 0; ww < 4; ++ww) {
                if (sb[ww] >= 0)
                    atomicMax(&pooled[sb[ww] * 32 + t], __float_as_uint(smax[ww][t]));
            }
        }
    }
}

// ---------------- final: out[64][4] = pooled[64][32] @ Wlin[32][4] + blin ----------------
__global__ __launch_bounds__(NTHREADS) void final_kernel(const float* __restrict__ pooled,
                                                         const float* __restrict__ Wlin,
                                                         const float* __restrict__ blin,
                                                         float* __restrict__ out) {
    int t = threadIdx.x;  // 256 = 64 graphs * 4 cols
    int g = t >> 2, c = t & 3;
    float s = blin[c];
    #pragma unroll
    for (int j = 0; j < 32; ++j) s += pooled[g * 32 + j] * Wlin[j * 4 + c];
    out[g * 4 + c] = s;
}

extern "C" void kernel_launch(void* const* d_in, const int* in_sizes, int n_in,
                              void* d_out, int out_size, void* d_ws, size_t ws_size,
                              hipStream_t stream) {
    const float* x     = (const float*)d_in[0];
    const int*   ei    = (const int*)d_in[1];
    const float* ew    = (const float*)d_in[2];
    const int*   batch = (const int*)d_in[3];
    const float* W1    = (const float*)d_in[4];
    const float* b1    = (const float*)d_in[5];
    const float* W2    = (const float*)d_in[6];
    const float* b2    = (const float*)d_in[7];
    const float* Wlin  = (const float*)d_in[8];
    const float* blin  = (const float*)d_in[9];
    float* out = (float*)d_out;

    const int E = in_sizes[2];   // 3200000
    const int n = in_sizes[3];   // 100000
    const int* src = ei;
    const int* dst = ei + E;

    const int nbuckets = (n + 511) >> BSHIFT;            // 196
    const int chunk = (E + NBP - 1) / NBP;               // 6250
    const int scanlen = nbuckets * NBP;                  // 100352
    const int nchunks = (scanlen + SCAN_CHUNK - 1) / SCAN_CHUNK;  // 98

    // workspace layout (4-byte units)
    auto al = [](size_t v) { return (v + 63) & ~(size_t)63; };
    float* ws = (float*)d_ws;
    size_t off = 0;
    unsigned int* cnt2d  = (unsigned int*)(ws + off); off += al(scanlen);
    unsigned int* base2d = (unsigned int*)(ws + off); off += al(scanlen);
    unsigned int* bsum   = (unsigned int*)(ws + off); off += al(256);
    float* dinv    = ws + off; off += al(n);
    int*   rowptr  = (int*)(ws + off); off += al(n + 1);
    unsigned int* meta = (unsigned int*)(ws + off); off += al(E);
    unsigned short* g1 = (unsigned short*)(ws + off); off += al((size_t)n * 32);  // bf16 n*64
    unsigned short* y1 = (unsigned short*)(ws + off); off += al((size_t)n * 32);  // bf16 n*64
    int2*  pairs   = (int2*)(ws + off); off += al((size_t)E * 2);
    float* pooled  = ws + off; off += al(64 * 32);
    unsigned short* g2 = g1;    // g1 dead after agg1; gemm2 overwrites with g2 (bf16 n*32)

    hipMemsetAsync(pooled, 0, 64 * 32 * sizeof(float), stream);

    // CSR build (no global atomics)
    p1_count_kernel<<<NBP, NTHREADS, 0, stream>>>(dst, cnt2d, E, nbuckets, chunk);
    scan1_kernel<<<nchunks, NTHREADS, 0, stream>>>(cnt2d, base2d, bsum, scanlen);
    scan2_kernel<<<1, NTHREADS, 0, stream>>>(bsum, nchunks);
    scan3_kernel<<<(scanlen + 255) / 256, NTHREADS, 0, stream>>>(base2d, bsum, scanlen);
    p2_scatter_kernel<<<NBP, NTHREADS, 0, stream>>>(src, dst, ew, cnt2d, base2d, pairs, E, nbuckets, chunk);
    p3_csr_kernel<<<nbuckets, 1024, 0, stream>>>(pairs, base2d, meta, rowptr, dinv, n, E, nbuckets);

    // layer 1
    gemm1_kernel<<<(n + 127) / 128, NTHREADS, 0, stream>>>(x, W1, dinv, g1, n);
    agg1_csr_kernel<<<(n + 3) / 4, NTHREADS, 0, stream>>>(rowptr, meta, g1, dinv, b1, y1, n);

    // layer 2
    gemm2_kernel<<<(n + 63) / 64, NTHREADS, 0, stream>>>(y1, W2, dinv, g2, n);
    agg2_csr_pool_kernel<<<(n + 3) / 4, NTHREADS, 0, stream>>>(
        rowptr, meta, g2, dinv, b2, batch, (unsigned int*)pooled, n);

    final_kernel<<<1, NTHREADS, 0, stream>>>(pooled, Wlin, blin, out);
}